// Round 1
// baseline (5247.094 us; speedup 1.0000x reference)
//
#include <hip/hip_runtime.h>
#include <math.h>

#define C64 64
#define CIN 66
#define NCLS 101
#define SEG_BLOCKS 1024   // fixed grid for segmax64 (deterministic stats slots)

// ---------------- CSR build ----------------

__global__ void count_kernel(const int* __restrict__ dst, int* __restrict__ counts, int E) {
    int e = blockIdx.x * blockDim.x + threadIdx.x;
    if (e < E) atomicAdd(&counts[dst[e]], 1);
}

__global__ void scan_kernel(const int* __restrict__ counts, int* __restrict__ offs,
                            int* __restrict__ wp, int N) {
    __shared__ int sums[1024];
    int tid = threadIdx.x;
    int chunk = (N + 1023) / 1024;
    int lo = tid * chunk;
    int hi = lo + chunk; if (hi > N) hi = N;
    int s = 0;
    for (int i = lo; i < hi; ++i) s += counts[i];
    sums[tid] = s;
    __syncthreads();
    if (tid == 0) {
        int run = 0;
        for (int i = 0; i < 1024; ++i) { int t = sums[i]; sums[i] = run; run += t; }
    }
    __syncthreads();
    int run = sums[tid];
    for (int i = lo; i < hi; ++i) { offs[i] = run; wp[i] = run; run += counts[i]; }
    if (hi == N) offs[N] = run;   // all such threads write the same total
}

__global__ void fill_kernel(const int* __restrict__ src, const int* __restrict__ dst,
                            int* __restrict__ wp, int* __restrict__ csr, int E) {
    int e = blockIdx.x * blockDim.x + threadIdx.x;
    if (e < E) {
        int p = atomicAdd(&wp[dst[e]], 1);
        csr[p] = src[e];
    }
}

// ---------------- node-side GEMM: U = [feat|pos2] @ W^T + b ----------------
// feat: N x 64, pos: N x 3 (cols 0,1 used), W: OD x 66, bias: OD, U: N x OD

__global__ __launch_bounds__(256)
void gemm66(const float* __restrict__ feat, const float* __restrict__ pos,
            const float* __restrict__ W, const float* __restrict__ bias,
            float* __restrict__ U, int N, int OD) {
    __shared__ __attribute__((aligned(16))) float As[64][68];
    __shared__ __attribute__((aligned(16))) float Ws[64][68];
    int row0 = blockIdx.x * 64;
    int c0   = blockIdx.y * 64;
    int tid  = threadIdx.x;

    for (int idx = tid; idx < 64 * 66; idx += 256) {
        int r = idx / 66, k = idx - r * 66;
        int grow = row0 + r;
        float v = 0.f;
        if (grow < N) v = (k < 64) ? feat[(size_t)grow * 64 + k] : pos[(size_t)grow * 3 + (k - 64)];
        As[r][k] = v;
    }
    for (int idx = tid; idx < 64 * 66; idx += 256) {
        int c = idx / 66, k = idx - c * 66;
        float v = 0.f;
        if (c0 + c < OD) v = W[(size_t)(c0 + c) * 66 + k];
        Ws[c][k] = v;
    }
    __syncthreads();

    int ci = tid & 63;
    int ty = tid >> 6;
    float acc[16];
#pragma unroll
    for (int r = 0; r < 16; ++r) acc[r] = 0.f;

#pragma unroll
    for (int kk = 0; kk < 16; ++kk) {
        float4 w4 = *(const float4*)&Ws[ci][kk * 4];
#pragma unroll
        for (int r = 0; r < 16; ++r) {
            float4 a4 = *(const float4*)&As[ty * 16 + r][kk * 4];
            acc[r] += a4.x * w4.x + a4.y * w4.y + a4.z * w4.z + a4.w * w4.w;
        }
    }
    {
        float w0 = Ws[ci][64], w1 = Ws[ci][65];
#pragma unroll
        for (int r = 0; r < 16; ++r)
            acc[r] += As[ty * 16 + r][64] * w0 + As[ty * 16 + r][65] * w1;
    }

    int c = c0 + ci;
    if (c < OD) {
        float b = bias[c];
#pragma unroll
        for (int r = 0; r < 16; ++r) {
            int grow = row0 + ty * 16 + r;
            if (grow < N) U[(size_t)grow * OD + c] = acc[r] + b;
        }
    }
}

// ---------------- segment max, OD=64, lane = channel ----------------

template <bool STATS>
__global__ __launch_bounds__(256)
void segmax64(const float* __restrict__ U, const float* __restrict__ pos,
              const float* __restrict__ W, const int* __restrict__ offs,
              const int* __restrict__ csr, float* __restrict__ out,
              float* __restrict__ partials, int N) {
    int lane = threadIdx.x & 63;
    int wv   = threadIdx.x >> 6;
    int gw   = blockIdx.x * 4 + wv;
    int nw   = gridDim.x * 4;
    float wp0 = W[lane * 66 + 64];
    float wp1 = W[lane * 66 + 65];
    float sum = 0.f, sq = 0.f;
    for (int i = gw; i < N; i += nw) {
        int s0 = offs[i], s1 = offs[i + 1];
        float m = -INFINITY;
        for (int e = s0; e < s1; ++e) {
            int j = csr[e];
            m = fmaxf(m, U[(size_t)j * 64 + lane]);
        }
        float val = 0.f;
        if (s1 > s0) val = m - (pos[i * 3] * wp0 + pos[i * 3 + 1] * wp1);
        out[(size_t)i * 64 + lane] = val;
        if (STATS) { sum += val; sq += val * val; }
    }
    if (STATS) {
        __shared__ float ls[4][64];
        __shared__ float lq[4][64];
        ls[wv][lane] = sum; lq[wv][lane] = sq;
        __syncthreads();
        if (wv == 0) {
            float s = ls[0][lane] + ls[1][lane] + ls[2][lane] + ls[3][lane];
            float q = lq[0][lane] + lq[1][lane] + lq[2][lane] + lq[3][lane];
            partials[blockIdx.x * 128 + lane]      = s;
            partials[blockIdx.x * 128 + 64 + lane] = q;
        }
    }
}

// ---------------- segment max, OD=101 (cls head) ----------------

__global__ __launch_bounds__(256)
void segmax_cls(const float* __restrict__ U, const float* __restrict__ pos,
                const float* __restrict__ W, const int* __restrict__ offs,
                const int* __restrict__ csr, float* __restrict__ out, int N) {
    int lane = threadIdx.x & 127;   // channel
    if (lane >= NCLS) return;       // no barriers below: safe
    int g  = threadIdx.x >> 7;
    int gg = blockIdx.x * 2 + g;
    int ng = gridDim.x * 2;
    float wp0 = W[lane * 66 + 64];
    float wp1 = W[lane * 66 + 65];
    for (int i = gg; i < N; i += ng) {
        int s0 = offs[i], s1 = offs[i + 1];
        float m = -INFINITY;
        for (int e = s0; e < s1; ++e) {
            int j = csr[e];
            m = fmaxf(m, U[(size_t)j * NCLS + lane]);
        }
        float val = 0.f;
        if (s1 > s0) val = m - (pos[i * 3] * wp0 + pos[i * 3 + 1] * wp1);
        out[(size_t)i * NCLS + lane] = val;
    }
}

// ---------------- segment max, small OD (4 / 1) ----------------

__global__ void segmax_small(const float* __restrict__ U, const float* __restrict__ pos,
                             const float* __restrict__ W, const int* __restrict__ offs,
                             const int* __restrict__ csr, float* __restrict__ out,
                             int N, int OD) {
    int t = blockIdx.x * blockDim.x + threadIdx.x;
    if (t >= N * OD) return;
    int i = t / OD;
    int c = t - i * OD;
    int s0 = offs[i], s1 = offs[i + 1];
    float m = -INFINITY;
    for (int e = s0; e < s1; ++e) m = fmaxf(m, U[(size_t)csr[e] * OD + c]);
    float val = 0.f;
    if (s1 > s0) val = m - (pos[i * 3] * W[c * 66 + 64] + pos[i * 3 + 1] * W[c * 66 + 65]);
    out[t] = val;
}

// ---------------- BN finalize (deterministic serial reduce) ----------------

__global__ void bn_finalize(const float* __restrict__ partials, int nb, int N,
                            const float* __restrict__ g, const float* __restrict__ be,
                            float* __restrict__ ab) {
    int c = threadIdx.x;   // 64 threads
    double s = 0.0, q = 0.0;
    for (int b = 0; b < nb; ++b) {
        s += (double)partials[b * 128 + c];
        q += (double)partials[b * 128 + 64 + c];
    }
    double invN = 1.0 / (double)N;
    float m = (float)(s * invN);
    float v = (float)(q * invN) - m * m;
    float a = g[c] * rsqrtf(v + 1e-5f);
    ab[c]      = a;
    ab[64 + c] = be[c] - m * a;
}

// ---------------- normalize + relu ----------------

__global__ void norm_relu(const float* __restrict__ s, const float* __restrict__ ab,
                          float* __restrict__ h, int total4) {
    int t = blockIdx.x * blockDim.x + threadIdx.x;
    if (t >= total4) return;
    float4 v = *(const float4*)&s[(size_t)t * 4];
    int c = (t * 4) & 63;
    float4 r;
    r.x = fmaxf(0.f, v.x * ab[c + 0] + ab[64 + c + 0]);
    r.y = fmaxf(0.f, v.y * ab[c + 1] + ab[64 + c + 1]);
    r.z = fmaxf(0.f, v.z * ab[c + 2] + ab[64 + c + 2]);
    r.w = fmaxf(0.f, v.w * ab[c + 3] + ab[64 + c + 3]);
    *(float4*)&h[(size_t)t * 4] = r;
}

// ---------------- launch ----------------

extern "C" void kernel_launch(void* const* d_in, const int* in_sizes, int n_in,
                              void* d_out, int out_size, void* d_ws, size_t ws_size,
                              hipStream_t stream) {
    const float* x       = (const float*)d_in[0];
    const float* pos     = (const float*)d_in[1];
    const int*   ei      = (const int*)d_in[2];
    const float* W_stem  = (const float*)d_in[3];
    const float* b_stem  = (const float*)d_in[4];
    const float* W_conv1 = (const float*)d_in[5];
    const float* b_conv1 = (const float*)d_in[6];
    const float* W_conv2 = (const float*)d_in[7];
    const float* b_conv2 = (const float*)d_in[8];
    const float* W_regr  = (const float*)d_in[9];
    const float* b_regr  = (const float*)d_in[10];
    const float* W_cls   = (const float*)d_in[11];
    const float* b_cls   = (const float*)d_in[12];
    const float* W_obj   = (const float*)d_in[13];
    const float* b_obj   = (const float*)d_in[14];
    const float* g_stem  = (const float*)d_in[15];
    const float* be_stem = (const float*)d_in[16];
    const float* g_conv1 = (const float*)d_in[17];
    const float* be_conv1= (const float*)d_in[18];
    const float* g_conv2 = (const float*)d_in[19];
    const float* be_conv2= (const float*)d_in[20];

    const int N = in_sizes[0] / 64;
    const int E = in_sizes[2] / 2;
    const int* src = ei;
    const int* dst = ei + E;

    // ---- workspace layout (each region 256B aligned) ----
    char* ws = (char*)d_ws;
    size_t off = 0;
    auto carve = [&](size_t bytes) -> char* {
        char* p = ws + off;
        off += (bytes + 255) & ~(size_t)255;
        return p;
    };
    int*   counts   = (int*)carve((size_t)(N + 1) * 4);
    int*   offs     = (int*)carve((size_t)(N + 1) * 4);
    int*   wp       = (int*)carve((size_t)N * 4);
    int*   csr      = (int*)carve((size_t)E * 4);
    float* bufA     = (float*)carve((size_t)N * 64 * 4);   // U_stem -> h ; (with bufB) aliased by U_cls
    float* bufB     = (float*)carve((size_t)N * 64 * 4);   // s_stem -> s1 -> s2   (contiguous after bufA)
    float* bufC     = (float*)carve((size_t)N * 64 * 4);   // U1 -> x1
    float* bufD     = (float*)carve((size_t)N * 64 * 4);   // U2 -> x2
    float* uSmall   = (float*)carve((size_t)N * 5 * 4);    // U_regr (N*4) + U_obj (N*1)
    float* partials = (float*)carve((size_t)SEG_BLOCKS * 128 * 4);
    float* ab       = (float*)carve(128 * 4);
    float* uCls     = bufA;            // N*101 floats fit in bufA+bufB (contiguous)
    float* uRegr    = uSmall;
    float* uObj     = uSmall + (size_t)N * 4;

    float* out_cls = (float*)d_out;                       // N x 101
    float* out_reg = out_cls + (size_t)N * NCLS;          // N x 4
    float* out_obj = out_reg + (size_t)N * 4;             // N x 1

    const int eg = (E + 255) / 256;
    const dim3 blk(256);

    // ---- CSR build ----
    hipMemsetAsync(counts, 0, (size_t)(N + 1) * 4, stream);
    count_kernel<<<eg, blk, 0, stream>>>(dst, counts, E);
    scan_kernel<<<1, 1024, 0, stream>>>(counts, offs, wp, N);
    fill_kernel<<<eg, blk, 0, stream>>>(src, dst, wp, csr, E);

    const int ng64 = (N + 63) / 64;
    const int nr4  = (N * 64 / 4 + 255) / 256;

    // ---- stem ----
    gemm66<<<dim3(ng64, 1), blk, 0, stream>>>(x, pos, W_stem, b_stem, bufA, N, 64);
    segmax64<true><<<SEG_BLOCKS, blk, 0, stream>>>(bufA, pos, W_stem, offs, csr, bufB, partials, N);
    bn_finalize<<<1, 64, 0, stream>>>(partials, SEG_BLOCKS, N, g_stem, be_stem, ab);
    norm_relu<<<nr4, blk, 0, stream>>>(bufB, ab, bufA, N * 64 / 4);           // h = bufA

    // ---- conv1 / conv2 ----
    gemm66<<<dim3(ng64, 1), blk, 0, stream>>>(bufA, pos, W_conv1, b_conv1, bufC, N, 64);
    gemm66<<<dim3(ng64, 1), blk, 0, stream>>>(bufA, pos, W_conv2, b_conv2, bufD, N, 64);

    segmax64<true><<<SEG_BLOCKS, blk, 0, stream>>>(bufC, pos, W_conv1, offs, csr, bufB, partials, N);
    bn_finalize<<<1, 64, 0, stream>>>(partials, SEG_BLOCKS, N, g_conv1, be_conv1, ab);
    norm_relu<<<nr4, blk, 0, stream>>>(bufB, ab, bufC, N * 64 / 4);           // x1 = bufC

    segmax64<true><<<SEG_BLOCKS, blk, 0, stream>>>(bufD, pos, W_conv2, offs, csr, bufB, partials, N);
    bn_finalize<<<1, 64, 0, stream>>>(partials, SEG_BLOCKS, N, g_conv2, be_conv2, ab);
    norm_relu<<<nr4, blk, 0, stream>>>(bufB, ab, bufD, N * 64 / 4);           // x2 = bufD

    // ---- heads ----
    gemm66<<<dim3(ng64, 1), blk, 0, stream>>>(bufC, pos, W_regr, b_regr, uRegr, N, 4);
    gemm66<<<dim3(ng64, 1), blk, 0, stream>>>(bufC, pos, W_obj,  b_obj,  uObj,  N, 1);
    gemm66<<<dim3(ng64, 2), blk, 0, stream>>>(bufD, pos, W_cls,  b_cls,  uCls,  N, NCLS);

    segmax_cls<<<SEG_BLOCKS, blk, 0, stream>>>(uCls, pos, W_cls, offs, csr, out_cls, N);
    segmax_small<<<(N * 4 + 255) / 256, blk, 0, stream>>>(uRegr, pos, W_regr, offs, csr, out_reg, N, 4);
    segmax_small<<<(N + 255) / 256, blk, 0, stream>>>(uObj, pos, W_obj, offs, csr, out_obj, N, 1);
}

// Round 2
// 2084.955 us; speedup vs baseline: 2.5166x; 2.5166x over previous
//
#include <hip/hip_runtime.h>
#include <math.h>

#define C64 64
#define CIN 66
#define NCLS 101
#define SEG_BLOCKS 1024   // fixed grid for segmax64 (deterministic stats slots)

typedef float f4 __attribute__((ext_vector_type(4)));

// ---------------- CSR build ----------------

__global__ void count_kernel(const int* __restrict__ dst, int* __restrict__ counts, int E) {
    int e = blockIdx.x * blockDim.x + threadIdx.x;
    if (e < E) atomicAdd(&counts[dst[e]], 1);
}

__global__ void scan_kernel(const int* __restrict__ counts, int* __restrict__ offs,
                            int* __restrict__ wp, int N) {
    __shared__ int sums[1024];
    int tid = threadIdx.x;
    int chunk = (N + 1023) / 1024;
    int lo = tid * chunk;
    int hi = lo + chunk; if (hi > N) hi = N;
    int s = 0;
    for (int i = lo; i < hi; ++i) s += counts[i];
    sums[tid] = s;
    __syncthreads();
    if (tid == 0) {
        int run = 0;
        for (int i = 0; i < 1024; ++i) { int t = sums[i]; sums[i] = run; run += t; }
    }
    __syncthreads();
    int run = sums[tid];
    for (int i = lo; i < hi; ++i) { offs[i] = run; wp[i] = run; run += counts[i]; }
    if (hi == N) offs[N] = run;   // all such threads write the same total
}

__global__ void fill_kernel(const int* __restrict__ src, const int* __restrict__ dst,
                            int* __restrict__ wp, int* __restrict__ csr, int E) {
    int e = blockIdx.x * blockDim.x + threadIdx.x;
    if (e < E) {
        int p = atomicAdd(&wp[dst[e]], 1);
        csr[p] = src[e];
    }
}

// ---------------- node-side GEMM: U = [feat|pos2] @ W^T + b ----------------
// feat: N x 64, pos: N x 3 (cols 0,1 used), W: OD x 66, bias: OD, U: N x OD
// 64x64 output tile per block, 256 threads, each thread a 4x4 register tile.
// ~50 live VGPRs — the round-1 version spilled (VGPR=256, 2.6GB scratch traffic).

__global__ __launch_bounds__(256)
void gemm66(const float* __restrict__ feat, const float* __restrict__ pos,
            const float* __restrict__ W, const float* __restrict__ bias,
            float* __restrict__ U, int N, int OD) {
    __shared__ __attribute__((aligned(16))) float As[64][68];   // [row][k], stride 272B (16B-aligned)
    __shared__ __attribute__((aligned(16))) float Wt[66][68];   // [k][col] (transposed W)
    int row0 = blockIdx.x * 64;
    int c0b  = blockIdx.y * 64;
    int tid  = threadIdx.x;

    // stage A: coalesced global read (k contiguous per lane-group)
    for (int idx = tid; idx < 64 * 66; idx += 256) {
        int r = idx / 66, k = idx - r * 66;
        int grow = row0 + r;
        float v = 0.f;
        if (grow < N) v = (k < 64) ? feat[(size_t)grow * 64 + k] : pos[(size_t)grow * 3 + (k - 64)];
        As[r][k] = v;
    }
    // stage W transposed: Wt[k][c]  (coalesced global read of W[c][k])
    for (int idx = tid; idx < 64 * 66; idx += 256) {
        int c = idx / 66, k = idx - c * 66;
        float v = 0.f;
        if (c0b + c < OD) v = W[(size_t)(c0b + c) * 66 + k];
        Wt[k][c] = v;
    }
    __syncthreads();

    const int cx = (tid & 15) * 4;   // col offset in tile
    const int ry = (tid >> 4) * 4;   // row offset in tile

    f4 acc[4];
#pragma unroll
    for (int i = 0; i < 4; ++i) acc[i] = (f4)(0.f);

#pragma unroll 2
    for (int k = 0; k < 64; k += 4) {
        f4 a[4], w[4];
#pragma unroll
        for (int i = 0; i < 4; ++i) a[i] = *(const f4*)&As[ry + i][k];      // broadcast-heavy, conflict-free
#pragma unroll
        for (int kk = 0; kk < 4; ++kk) w[kk] = *(const f4*)&Wt[k + kk][cx]; // 64 consec floats/wave: 2-way, free
#pragma unroll
        for (int i = 0; i < 4; ++i) {
#pragma unroll
            for (int kk = 0; kk < 4; ++kk) {
                acc[i] += a[i][kk] * w[kk];   // vector FMA over the 4 cols
            }
        }
    }
    // k = 64, 65 (pos channels)
#pragma unroll
    for (int k2 = 64; k2 < 66; ++k2) {
        f4 w = *(const f4*)&Wt[k2][cx];
#pragma unroll
        for (int i = 0; i < 4; ++i) acc[i] += As[ry + i][k2] * w;
    }

    // epilogue: bias + guarded scalar stores
#pragma unroll
    for (int i = 0; i < 4; ++i) {
        int grow = row0 + ry + i;
        if (grow >= N) break;
#pragma unroll
        for (int j = 0; j < 4; ++j) {
            int c = c0b + cx + j;
            if (c < OD) U[(size_t)grow * OD + c] = acc[i][j] + bias[c];
        }
    }
}

// ---------------- segment max, OD=64, lane = channel ----------------

template <bool STATS>
__global__ __launch_bounds__(256)
void segmax64(const float* __restrict__ U, const float* __restrict__ pos,
              const float* __restrict__ W, const int* __restrict__ offs,
              const int* __restrict__ csr, float* __restrict__ out,
              float* __restrict__ partials, int N) {
    int lane = threadIdx.x & 63;
    int wv   = threadIdx.x >> 6;
    int gw   = blockIdx.x * 4 + wv;
    int nw   = gridDim.x * 4;
    float wp0 = W[lane * 66 + 64];
    float wp1 = W[lane * 66 + 65];
    float sum = 0.f, sq = 0.f;
    for (int i = gw; i < N; i += nw) {
        int s0 = offs[i], s1 = offs[i + 1];
        float m = -INFINITY;
        for (int e = s0; e < s1; ++e) {
            int j = csr[e];
            m = fmaxf(m, U[(size_t)j * 64 + lane]);
        }
        float val = 0.f;
        if (s1 > s0) val = m - (pos[i * 3] * wp0 + pos[i * 3 + 1] * wp1);
        out[(size_t)i * 64 + lane] = val;
        if (STATS) { sum += val; sq += val * val; }
    }
    if (STATS) {
        __shared__ float ls[4][64];
        __shared__ float lq[4][64];
        ls[wv][lane] = sum; lq[wv][lane] = sq;
        __syncthreads();
        if (wv == 0) {
            float s = ls[0][lane] + ls[1][lane] + ls[2][lane] + ls[3][lane];
            float q = lq[0][lane] + lq[1][lane] + lq[2][lane] + lq[3][lane];
            partials[blockIdx.x * 128 + lane]      = s;
            partials[blockIdx.x * 128 + 64 + lane] = q;
        }
    }
}

// ---------------- segment max, OD=101 (cls head) ----------------

__global__ __launch_bounds__(256)
void segmax_cls(const float* __restrict__ U, const float* __restrict__ pos,
                const float* __restrict__ W, const int* __restrict__ offs,
                const int* __restrict__ csr, float* __restrict__ out, int N) {
    int lane = threadIdx.x & 127;   // channel
    if (lane >= NCLS) return;       // no barriers below: safe
    int g  = threadIdx.x >> 7;
    int gg = blockIdx.x * 2 + g;
    int ng = gridDim.x * 2;
    float wp0 = W[lane * 66 + 64];
    float wp1 = W[lane * 66 + 65];
    for (int i = gg; i < N; i += ng) {
        int s0 = offs[i], s1 = offs[i + 1];
        float m = -INFINITY;
        for (int e = s0; e < s1; ++e) {
            int j = csr[e];
            m = fmaxf(m, U[(size_t)j * NCLS + lane]);
        }
        float val = 0.f;
        if (s1 > s0) val = m - (pos[i * 3] * wp0 + pos[i * 3 + 1] * wp1);
        out[(size_t)i * NCLS + lane] = val;
    }
}

// ---------------- segment max, small OD (4 / 1) ----------------

__global__ void segmax_small(const float* __restrict__ U, const float* __restrict__ pos,
                             const float* __restrict__ W, const int* __restrict__ offs,
                             const int* __restrict__ csr, float* __restrict__ out,
                             int N, int OD) {
    int t = blockIdx.x * blockDim.x + threadIdx.x;
    if (t >= N * OD) return;
    int i = t / OD;
    int c = t - i * OD;
    int s0 = offs[i], s1 = offs[i + 1];
    float m = -INFINITY;
    for (int e = s0; e < s1; ++e) m = fmaxf(m, U[(size_t)csr[e] * OD + c]);
    float val = 0.f;
    if (s1 > s0) val = m - (pos[i * 3] * W[c * 66 + 64] + pos[i * 3 + 1] * W[c * 66 + 65]);
    out[t] = val;
}

// ---------------- BN finalize (deterministic serial reduce) ----------------

__global__ void bn_finalize(const float* __restrict__ partials, int nb, int N,
                            const float* __restrict__ g, const float* __restrict__ be,
                            float* __restrict__ ab) {
    int c = threadIdx.x;   // 64 threads
    double s = 0.0, q = 0.0;
    for (int b = 0; b < nb; ++b) {
        s += (double)partials[b * 128 + c];
        q += (double)partials[b * 128 + 64 + c];
    }
    double invN = 1.0 / (double)N;
    float m = (float)(s * invN);
    float v = (float)(q * invN) - m * m;
    float a = g[c] * rsqrtf(v + 1e-5f);
    ab[c]      = a;
    ab[64 + c] = be[c] - m * a;
}

// ---------------- normalize + relu ----------------

__global__ void norm_relu(const float* __restrict__ s, const float* __restrict__ ab,
                          float* __restrict__ h, int total4) {
    int t = blockIdx.x * blockDim.x + threadIdx.x;
    if (t >= total4) return;
    float4 v = *(const float4*)&s[(size_t)t * 4];
    int c = (t * 4) & 63;
    float4 r;
    r.x = fmaxf(0.f, v.x * ab[c + 0] + ab[64 + c + 0]);
    r.y = fmaxf(0.f, v.y * ab[c + 1] + ab[64 + c + 1]);
    r.z = fmaxf(0.f, v.z * ab[c + 2] + ab[64 + c + 2]);
    r.w = fmaxf(0.f, v.w * ab[c + 3] + ab[64 + c + 3]);
    *(float4*)&h[(size_t)t * 4] = r;
}

// ---------------- launch ----------------

extern "C" void kernel_launch(void* const* d_in, const int* in_sizes, int n_in,
                              void* d_out, int out_size, void* d_ws, size_t ws_size,
                              hipStream_t stream) {
    const float* x       = (const float*)d_in[0];
    const float* pos     = (const float*)d_in[1];
    const int*   ei      = (const int*)d_in[2];
    const float* W_stem  = (const float*)d_in[3];
    const float* b_stem  = (const float*)d_in[4];
    const float* W_conv1 = (const float*)d_in[5];
    const float* b_conv1 = (const float*)d_in[6];
    const float* W_conv2 = (const float*)d_in[7];
    const float* b_conv2 = (const float*)d_in[8];
    const float* W_regr  = (const float*)d_in[9];
    const float* b_regr  = (const float*)d_in[10];
    const float* W_cls   = (const float*)d_in[11];
    const float* b_cls   = (const float*)d_in[12];
    const float* W_obj   = (const float*)d_in[13];
    const float* b_obj   = (const float*)d_in[14];
    const float* g_stem  = (const float*)d_in[15];
    const float* be_stem = (const float*)d_in[16];
    const float* g_conv1 = (const float*)d_in[17];
    const float* be_conv1= (const float*)d_in[18];
    const float* g_conv2 = (const float*)d_in[19];
    const float* be_conv2= (const float*)d_in[20];

    const int N = in_sizes[0] / 64;
    const int E = in_sizes[2] / 2;
    const int* src = ei;
    const int* dst = ei + E;

    // ---- workspace layout (each region 256B aligned) ----
    char* ws = (char*)d_ws;
    size_t off = 0;
    auto carve = [&](size_t bytes) -> char* {
        char* p = ws + off;
        off += (bytes + 255) & ~(size_t)255;
        return p;
    };
    int*   counts   = (int*)carve((size_t)(N + 1) * 4);
    int*   offs     = (int*)carve((size_t)(N + 1) * 4);
    int*   wp       = (int*)carve((size_t)N * 4);
    int*   csr      = (int*)carve((size_t)E * 4);
    float* bufA     = (float*)carve((size_t)N * 64 * 4);   // U_stem -> h ; (with bufB) aliased by U_cls
    float* bufB     = (float*)carve((size_t)N * 64 * 4);   // s_stem -> s1 -> s2   (contiguous after bufA)
    float* bufC     = (float*)carve((size_t)N * 64 * 4);   // U1 -> x1
    float* bufD     = (float*)carve((size_t)N * 64 * 4);   // U2 -> x2
    float* uSmall   = (float*)carve((size_t)N * 5 * 4);    // U_regr (N*4) + U_obj (N*1)
    float* partials = (float*)carve((size_t)SEG_BLOCKS * 128 * 4);
    float* ab       = (float*)carve(128 * 4);
    float* uCls     = bufA;            // N*101 floats fit in bufA+bufB (contiguous)
    float* uRegr    = uSmall;
    float* uObj     = uSmall + (size_t)N * 4;

    float* out_cls = (float*)d_out;                       // N x 101
    float* out_reg = out_cls + (size_t)N * NCLS;          // N x 4
    float* out_obj = out_reg + (size_t)N * 4;             // N x 1

    const int eg = (E + 255) / 256;
    const dim3 blk(256);

    // ---- CSR build ----
    hipMemsetAsync(counts, 0, (size_t)(N + 1) * 4, stream);
    count_kernel<<<eg, blk, 0, stream>>>(dst, counts, E);
    scan_kernel<<<1, 1024, 0, stream>>>(counts, offs, wp, N);
    fill_kernel<<<eg, blk, 0, stream>>>(src, dst, wp, csr, E);

    const int ng64 = (N + 63) / 64;
    const int nr4  = (N * 64 / 4 + 255) / 256;

    // ---- stem ----
    gemm66<<<dim3(ng64, 1), blk, 0, stream>>>(x, pos, W_stem, b_stem, bufA, N, 64);
    segmax64<true><<<SEG_BLOCKS, blk, 0, stream>>>(bufA, pos, W_stem, offs, csr, bufB, partials, N);
    bn_finalize<<<1, 64, 0, stream>>>(partials, SEG_BLOCKS, N, g_stem, be_stem, ab);
    norm_relu<<<nr4, blk, 0, stream>>>(bufB, ab, bufA, N * 64 / 4);           // h = bufA

    // ---- conv1 / conv2 ----
    gemm66<<<dim3(ng64, 1), blk, 0, stream>>>(bufA, pos, W_conv1, b_conv1, bufC, N, 64);
    gemm66<<<dim3(ng64, 1), blk, 0, stream>>>(bufA, pos, W_conv2, b_conv2, bufD, N, 64);

    segmax64<true><<<SEG_BLOCKS, blk, 0, stream>>>(bufC, pos, W_conv1, offs, csr, bufB, partials, N);
    bn_finalize<<<1, 64, 0, stream>>>(partials, SEG_BLOCKS, N, g_conv1, be_conv1, ab);
    norm_relu<<<nr4, blk, 0, stream>>>(bufB, ab, bufC, N * 64 / 4);           // x1 = bufC

    segmax64<true><<<SEG_BLOCKS, blk, 0, stream>>>(bufD, pos, W_conv2, offs, csr, bufB, partials, N);
    bn_finalize<<<1, 64, 0, stream>>>(partials, SEG_BLOCKS, N, g_conv2, be_conv2, ab);
    norm_relu<<<nr4, blk, 0, stream>>>(bufB, ab, bufD, N * 64 / 4);           // x2 = bufD

    // ---- heads ----
    gemm66<<<dim3(ng64, 1), blk, 0, stream>>>(bufC, pos, W_regr, b_regr, uRegr, N, 4);
    gemm66<<<dim3(ng64, 1), blk, 0, stream>>>(bufC, pos, W_obj,  b_obj,  uObj,  N, 1);
    gemm66<<<dim3(ng64, 2), blk, 0, stream>>>(bufD, pos, W_cls,  b_cls,  uCls,  N, NCLS);

    segmax_cls<<<SEG_BLOCKS, blk, 0, stream>>>(uCls, pos, W_cls, offs, csr, out_cls, N);
    segmax_small<<<(N * 4 + 255) / 256, blk, 0, stream>>>(uRegr, pos, W_regr, offs, csr, out_reg, N, 4);
    segmax_small<<<(N + 255) / 256, blk, 0, stream>>>(uObj, pos, W_obj, offs, csr, out_obj, N, 1);
}

// Round 3
// 1331.403 us; speedup vs baseline: 3.9410x; 1.5660x over previous
//
#include <hip/hip_runtime.h>
#include <math.h>

#define C64 64
#define CIN 66
#define NCLS 101
#define SEG_BLOCKS 1024   // fixed grid for segmax64 (deterministic stats slots)

typedef float f4 __attribute__((ext_vector_type(4)));

// ---------------- CSR build ----------------

__global__ void count_kernel(const int* __restrict__ dst, int* __restrict__ counts, int E) {
    int e = blockIdx.x * blockDim.x + threadIdx.x;
    if (e < E) atomicAdd(&counts[dst[e]], 1);
}

__global__ void scan_kernel(const int* __restrict__ counts, int* __restrict__ offs,
                            int* __restrict__ wp, int N) {
    __shared__ int sums[1024];
    int tid = threadIdx.x;
    int chunk = (N + 1023) / 1024;
    int lo = tid * chunk;
    int hi = lo + chunk; if (hi > N) hi = N;
    int s = 0;
    for (int i = lo; i < hi; ++i) s += counts[i];
    sums[tid] = s;
    __syncthreads();
    if (tid == 0) {
        int run = 0;
        for (int i = 0; i < 1024; ++i) { int t = sums[i]; sums[i] = run; run += t; }
    }
    __syncthreads();
    int run = sums[tid];
    for (int i = lo; i < hi; ++i) { offs[i] = run; wp[i] = run; run += counts[i]; }
    if (hi == N) offs[N] = run;   // all such threads write the same total
}

__global__ void fill_kernel(const int* __restrict__ src, const int* __restrict__ dst,
                            int* __restrict__ wp, int* __restrict__ csr, int E) {
    int e = blockIdx.x * blockDim.x + threadIdx.x;
    if (e < E) {
        int p = atomicAdd(&wp[dst[e]], 1);
        csr[p] = src[e];
    }
}

// ---------------- node-side GEMM: U = [feat|pos2] @ W^T + b ----------------
// feat: N x 64, pos: N x 3 (cols 0,1 used), W: OD x 66, bias: OD, U: N x OD
// 64x64 output tile per block, 256 threads, each thread a 4x4 register tile.

__global__ __launch_bounds__(256)
void gemm66(const float* __restrict__ feat, const float* __restrict__ pos,
            const float* __restrict__ W, const float* __restrict__ bias,
            float* __restrict__ U, int N, int OD) {
    __shared__ __attribute__((aligned(16))) float As[64][68];   // [row][k]
    __shared__ __attribute__((aligned(16))) float Wt[66][68];   // [k][col] (transposed W)
    int row0 = blockIdx.x * 64;
    int c0b  = blockIdx.y * 64;
    int tid  = threadIdx.x;

    for (int idx = tid; idx < 64 * 66; idx += 256) {
        int r = idx / 66, k = idx - r * 66;
        int grow = row0 + r;
        float v = 0.f;
        if (grow < N) v = (k < 64) ? feat[(size_t)grow * 64 + k] : pos[(size_t)grow * 3 + (k - 64)];
        As[r][k] = v;
    }
    for (int idx = tid; idx < 64 * 66; idx += 256) {
        int c = idx / 66, k = idx - c * 66;
        float v = 0.f;
        if (c0b + c < OD) v = W[(size_t)(c0b + c) * 66 + k];
        Wt[k][c] = v;
    }
    __syncthreads();

    const int cx = (tid & 15) * 4;   // col offset in tile
    const int ry = (tid >> 4) * 4;   // row offset in tile

    f4 acc[4];
#pragma unroll
    for (int i = 0; i < 4; ++i) acc[i] = (f4)(0.f);

#pragma unroll 2
    for (int k = 0; k < 64; k += 4) {
        f4 a[4], w[4];
#pragma unroll
        for (int i = 0; i < 4; ++i) a[i] = *(const f4*)&As[ry + i][k];
#pragma unroll
        for (int kk = 0; kk < 4; ++kk) w[kk] = *(const f4*)&Wt[k + kk][cx];
#pragma unroll
        for (int i = 0; i < 4; ++i) {
#pragma unroll
            for (int kk = 0; kk < 4; ++kk) {
                acc[i] += a[i][kk] * w[kk];
            }
        }
    }
#pragma unroll
    for (int k2 = 64; k2 < 66; ++k2) {
        f4 w = *(const f4*)&Wt[k2][cx];
#pragma unroll
        for (int i = 0; i < 4; ++i) acc[i] += As[ry + i][k2] * w;
    }

#pragma unroll
    for (int i = 0; i < 4; ++i) {
        int grow = row0 + ry + i;
        if (grow >= N) break;
#pragma unroll
        for (int j = 0; j < 4; ++j) {
            int c = c0b + cx + j;
            if (c < OD) U[(size_t)grow * OD + c] = acc[i][j] + bias[c];
        }
    }
}

// ---------------- segment max, OD=64, lane = channel ----------------

template <bool STATS>
__global__ __launch_bounds__(256)
void segmax64(const float* __restrict__ U, const float* __restrict__ pos,
              const float* __restrict__ W, const int* __restrict__ offs,
              const int* __restrict__ csr, float* __restrict__ out,
              float* __restrict__ partials, int N) {
    int lane = threadIdx.x & 63;
    int wv   = threadIdx.x >> 6;
    int gw   = blockIdx.x * 4 + wv;
    int nw   = gridDim.x * 4;
    float wp0 = W[lane * 66 + 64];
    float wp1 = W[lane * 66 + 65];
    float sum = 0.f, sq = 0.f;
    for (int i = gw; i < N; i += nw) {
        int s0 = offs[i], s1 = offs[i + 1];
        float m = -INFINITY;
        for (int e = s0; e < s1; ++e) {
            int j = csr[e];
            m = fmaxf(m, U[(size_t)j * 64 + lane]);
        }
        float val = 0.f;
        if (s1 > s0) val = m - (pos[i * 3] * wp0 + pos[i * 3 + 1] * wp1);
        out[(size_t)i * 64 + lane] = val;
        if (STATS) { sum += val; sq += val * val; }
    }
    if (STATS) {
        __shared__ float ls[4][64];
        __shared__ float lq[4][64];
        ls[wv][lane] = sum; lq[wv][lane] = sq;
        __syncthreads();
        if (wv == 0) {
            float s = ls[0][lane] + ls[1][lane] + ls[2][lane] + ls[3][lane];
            float q = lq[0][lane] + lq[1][lane] + lq[2][lane] + lq[3][lane];
            partials[blockIdx.x * 128 + lane]      = s;
            partials[blockIdx.x * 128 + 64 + lane] = q;
        }
    }
}

// ---------------- segment max, OD=101 (cls head) ----------------

__global__ __launch_bounds__(256)
void segmax_cls(const float* __restrict__ U, const float* __restrict__ pos,
                const float* __restrict__ W, const int* __restrict__ offs,
                const int* __restrict__ csr, float* __restrict__ out, int N) {
    int lane = threadIdx.x & 127;   // channel
    if (lane >= NCLS) return;       // no barriers below: safe
    int g  = threadIdx.x >> 7;
    int gg = blockIdx.x * 2 + g;
    int ng = gridDim.x * 2;
    float wp0 = W[lane * 66 + 64];
    float wp1 = W[lane * 66 + 65];
    for (int i = gg; i < N; i += ng) {
        int s0 = offs[i], s1 = offs[i + 1];
        float m = -INFINITY;
        for (int e = s0; e < s1; ++e) {
            int j = csr[e];
            m = fmaxf(m, U[(size_t)j * NCLS + lane]);
        }
        float val = 0.f;
        if (s1 > s0) val = m - (pos[i * 3] * wp0 + pos[i * 3 + 1] * wp1);
        out[(size_t)i * NCLS + lane] = val;
    }
}

// ---------------- segment max, small OD (4 / 1) ----------------

__global__ void segmax_small(const float* __restrict__ U, const float* __restrict__ pos,
                             const float* __restrict__ W, const int* __restrict__ offs,
                             const int* __restrict__ csr, float* __restrict__ out,
                             int N, int OD) {
    int t = blockIdx.x * blockDim.x + threadIdx.x;
    if (t >= N * OD) return;
    int i = t / OD;
    int c = t - i * OD;
    int s0 = offs[i], s1 = offs[i + 1];
    float m = -INFINITY;
    for (int e = s0; e < s1; ++e) m = fmaxf(m, U[(size_t)csr[e] * OD + c]);
    float val = 0.f;
    if (s1 > s0) val = m - (pos[i * 3] * W[c * 66 + 64] + pos[i * 3 + 1] * W[c * 66 + 65]);
    out[t] = val;
}

// ---------------- BN finalize: parallel tree reduce ----------------
// round-2's version was 1 wave doing 1024 serial cross-XCD loads = 262us each.
// Now: 1024 threads, thread t -> channel c=t&63, group g=t>>6; each group sums a
// fixed 64-block slice (pipelined independent loads), then fixed-order 16-way
// LDS reduce in doubles. Deterministic.

__global__ __launch_bounds__(1024)
void bn_finalize(const float* __restrict__ partials, int N,
                 const float* __restrict__ g, const float* __restrict__ be,
                 float* __restrict__ ab) {
    __shared__ double ls[16][64];
    __shared__ double lq[16][64];
    int t = threadIdx.x;
    int c  = t & 63;
    int gr = t >> 6;          // 0..15
    double s = 0.0, q = 0.0;
#pragma unroll 8
    for (int b = 0; b < 64; ++b) {
        int blk = gr * 64 + b;
        s += (double)partials[blk * 128 + c];
        q += (double)partials[blk * 128 + 64 + c];
    }
    ls[gr][c] = s; lq[gr][c] = q;
    __syncthreads();
    if (gr == 0) {
        double ss = 0.0, qq = 0.0;
#pragma unroll
        for (int i = 0; i < 16; ++i) { ss += ls[i][c]; qq += lq[i][c]; }
        double invN = 1.0 / (double)N;
        float m = (float)(ss * invN);
        float v = (float)(qq * invN) - m * m;
        float a = g[c] * rsqrtf(v + 1e-5f);
        ab[c]      = a;
        ab[64 + c] = be[c] - m * a;
    }
}

// ---------------- normalize + relu ----------------

__global__ void norm_relu(const float* __restrict__ s, const float* __restrict__ ab,
                          float* __restrict__ h, int total4) {
    int t = blockIdx.x * blockDim.x + threadIdx.x;
    if (t >= total4) return;
    float4 v = *(const float4*)&s[(size_t)t * 4];
    int c = (t * 4) & 63;
    float4 r;
    r.x = fmaxf(0.f, v.x * ab[c + 0] + ab[64 + c + 0]);
    r.y = fmaxf(0.f, v.y * ab[c + 1] + ab[64 + c + 1]);
    r.z = fmaxf(0.f, v.z * ab[c + 2] + ab[64 + c + 2]);
    r.w = fmaxf(0.f, v.w * ab[c + 3] + ab[64 + c + 3]);
    *(float4*)&h[(size_t)t * 4] = r;
}

// ---------------- launch ----------------

extern "C" void kernel_launch(void* const* d_in, const int* in_sizes, int n_in,
                              void* d_out, int out_size, void* d_ws, size_t ws_size,
                              hipStream_t stream) {
    const float* x       = (const float*)d_in[0];
    const float* pos     = (const float*)d_in[1];
    const int*   ei      = (const int*)d_in[2];
    const float* W_stem  = (const float*)d_in[3];
    const float* b_stem  = (const float*)d_in[4];
    const float* W_conv1 = (const float*)d_in[5];
    const float* b_conv1 = (const float*)d_in[6];
    const float* W_conv2 = (const float*)d_in[7];
    const float* b_conv2 = (const float*)d_in[8];
    const float* W_regr  = (const float*)d_in[9];
    const float* b_regr  = (const float*)d_in[10];
    const float* W_cls   = (const float*)d_in[11];
    const float* b_cls   = (const float*)d_in[12];
    const float* W_obj   = (const float*)d_in[13];
    const float* b_obj   = (const float*)d_in[14];
    const float* g_stem  = (const float*)d_in[15];
    const float* be_stem = (const float*)d_in[16];
    const float* g_conv1 = (const float*)d_in[17];
    const float* be_conv1= (const float*)d_in[18];
    const float* g_conv2 = (const float*)d_in[19];
    const float* be_conv2= (const float*)d_in[20];

    const int N = in_sizes[0] / 64;
    const int E = in_sizes[2] / 2;
    const int* src = ei;
    const int* dst = ei + E;

    // ---- workspace layout (each region 256B aligned) ----
    char* ws = (char*)d_ws;
    size_t off = 0;
    auto carve = [&](size_t bytes) -> char* {
        char* p = ws + off;
        off += (bytes + 255) & ~(size_t)255;
        return p;
    };
    int*   counts   = (int*)carve((size_t)(N + 1) * 4);
    int*   offs     = (int*)carve((size_t)(N + 1) * 4);
    int*   wp       = (int*)carve((size_t)N * 4);
    int*   csr      = (int*)carve((size_t)E * 4);
    float* bufA     = (float*)carve((size_t)N * 64 * 4);   // U_stem -> h ; (with bufB) aliased by U_cls
    float* bufB     = (float*)carve((size_t)N * 64 * 4);   // s_stem -> s1 -> s2
    float* bufC     = (float*)carve((size_t)N * 64 * 4);   // U1 -> x1
    float* bufD     = (float*)carve((size_t)N * 64 * 4);   // U2 -> x2
    float* uSmall   = (float*)carve((size_t)N * 5 * 4);    // U_regr (N*4) + U_obj (N*1)
    float* partials = (float*)carve((size_t)SEG_BLOCKS * 128 * 4);
    float* ab       = (float*)carve(128 * 4);
    float* uCls     = bufA;            // N*101 floats fit in bufA+bufB (contiguous)
    float* uRegr    = uSmall;
    float* uObj     = uSmall + (size_t)N * 4;

    float* out_cls = (float*)d_out;                       // N x 101
    float* out_reg = out_cls + (size_t)N * NCLS;          // N x 4
    float* out_obj = out_reg + (size_t)N * 4;             // N x 1

    const int eg = (E + 255) / 256;
    const dim3 blk(256);

    // ---- CSR build ----
    hipMemsetAsync(counts, 0, (size_t)(N + 1) * 4, stream);
    count_kernel<<<eg, blk, 0, stream>>>(dst, counts, E);
    scan_kernel<<<1, 1024, 0, stream>>>(counts, offs, wp, N);
    fill_kernel<<<eg, blk, 0, stream>>>(src, dst, wp, csr, E);

    const int ng64 = (N + 63) / 64;
    const int nr4  = (N * 64 / 4 + 255) / 256;

    // ---- stem ----
    gemm66<<<dim3(ng64, 1), blk, 0, stream>>>(x, pos, W_stem, b_stem, bufA, N, 64);
    segmax64<true><<<SEG_BLOCKS, blk, 0, stream>>>(bufA, pos, W_stem, offs, csr, bufB, partials, N);
    bn_finalize<<<1, 1024, 0, stream>>>(partials, N, g_stem, be_stem, ab);
    norm_relu<<<nr4, blk, 0, stream>>>(bufB, ab, bufA, N * 64 / 4);           // h = bufA

    // ---- conv1 / conv2 ----
    gemm66<<<dim3(ng64, 1), blk, 0, stream>>>(bufA, pos, W_conv1, b_conv1, bufC, N, 64);
    gemm66<<<dim3(ng64, 1), blk, 0, stream>>>(bufA, pos, W_conv2, b_conv2, bufD, N, 64);

    segmax64<true><<<SEG_BLOCKS, blk, 0, stream>>>(bufC, pos, W_conv1, offs, csr, bufB, partials, N);
    bn_finalize<<<1, 1024, 0, stream>>>(partials, N, g_conv1, be_conv1, ab);
    norm_relu<<<nr4, blk, 0, stream>>>(bufB, ab, bufC, N * 64 / 4);           // x1 = bufC

    segmax64<true><<<SEG_BLOCKS, blk, 0, stream>>>(bufD, pos, W_conv2, offs, csr, bufB, partials, N);
    bn_finalize<<<1, 1024, 0, stream>>>(partials, N, g_conv2, be_conv2, ab);
    norm_relu<<<nr4, blk, 0, stream>>>(bufB, ab, bufD, N * 64 / 4);           // x2 = bufD

    // ---- heads ----
    gemm66<<<dim3(ng64, 1), blk, 0, stream>>>(bufC, pos, W_regr, b_regr, uRegr, N, 4);
    gemm66<<<dim3(ng64, 1), blk, 0, stream>>>(bufC, pos, W_obj,  b_obj,  uObj,  N, 1);
    gemm66<<<dim3(ng64, 2), blk, 0, stream>>>(bufD, pos, W_cls,  b_cls,  uCls,  N, NCLS);

    segmax_cls<<<SEG_BLOCKS, blk, 0, stream>>>(uCls, pos, W_cls, offs, csr, out_cls, N);
    segmax_small<<<(N * 4 + 255) / 256, blk, 0, stream>>>(uRegr, pos, W_regr, offs, csr, out_reg, N, 4);
    segmax_small<<<(N + 255) / 256, blk, 0, stream>>>(uObj, pos, W_obj, offs, csr, out_obj, N, 1);
}

// Round 4
// 936.877 us; speedup vs baseline: 5.6006x; 1.4211x over previous
//
#include <hip/hip_runtime.h>
#include <math.h>

#define C64 64
#define CIN 66
#define NCLS 101
#define LDCLS 102          // padded row stride for U_cls (float2-aligned per lane)
#define SEG_BLOCKS 2048    // fixed grid for segmax kernels (deterministic stats slots)

typedef float f4 __attribute__((ext_vector_type(4)));
typedef float f2 __attribute__((ext_vector_type(2)));

// ---------------- CSR build ----------------

__global__ void count_kernel(const int* __restrict__ dst, int* __restrict__ counts, int E) {
    int e = blockIdx.x * blockDim.x + threadIdx.x;
    if (e < E) atomicAdd(&counts[dst[e]], 1);
}

__global__ void scan_kernel(const int* __restrict__ counts, int* __restrict__ offs,
                            int* __restrict__ wp, int N) {
    __shared__ int sums[1024];
    int tid = threadIdx.x;
    int chunk = (N + 1023) / 1024;
    int lo = tid * chunk;
    int hi = lo + chunk; if (hi > N) hi = N;
    int s = 0;
    for (int i = lo; i < hi; ++i) s += counts[i];
    sums[tid] = s;
    __syncthreads();
    if (tid == 0) {
        int run = 0;
        for (int i = 0; i < 1024; ++i) { int t = sums[i]; sums[i] = run; run += t; }
    }
    __syncthreads();
    int run = sums[tid];
    for (int i = lo; i < hi; ++i) { offs[i] = run; wp[i] = run; run += counts[i]; }
    if (hi == N) offs[N] = run;   // all such threads write the same total
}

__global__ void fill_kernel(const int* __restrict__ src, const int* __restrict__ dst,
                            int* __restrict__ wp, int* __restrict__ csr, int E) {
    int e = blockIdx.x * blockDim.x + threadIdx.x;
    if (e < E) {
        int p = atomicAdd(&wp[dst[e]], 1);
        csr[p] = src[e];
    }
}

// ---------------- node-side GEMM: U = [feat|pos2] @ W^T + b ----------------
// feat: N x 64, pos: N x 3 (cols 0,1 used), W: OD x 66, bias: OD, U: N x ldU

__global__ __launch_bounds__(256)
void gemm66(const float* __restrict__ feat, const float* __restrict__ pos,
            const float* __restrict__ W, const float* __restrict__ bias,
            float* __restrict__ U, int N, int OD, int ldU) {
    __shared__ __attribute__((aligned(16))) float As[64][68];   // [row][k]
    __shared__ __attribute__((aligned(16))) float Wt[66][68];   // [k][col] (transposed W)
    int row0 = blockIdx.x * 64;
    int c0b  = blockIdx.y * 64;
    int tid  = threadIdx.x;

    for (int idx = tid; idx < 64 * 66; idx += 256) {
        int r = idx / 66, k = idx - r * 66;
        int grow = row0 + r;
        float v = 0.f;
        if (grow < N) v = (k < 64) ? feat[(size_t)grow * 64 + k] : pos[(size_t)grow * 3 + (k - 64)];
        As[r][k] = v;
    }
    for (int idx = tid; idx < 64 * 66; idx += 256) {
        int c = idx / 66, k = idx - c * 66;
        float v = 0.f;
        if (c0b + c < OD) v = W[(size_t)(c0b + c) * 66 + k];
        Wt[k][c] = v;
    }
    __syncthreads();

    const int cx = (tid & 15) * 4;   // col offset in tile
    const int ry = (tid >> 4) * 4;   // row offset in tile

    f4 acc[4];
#pragma unroll
    for (int i = 0; i < 4; ++i) acc[i] = (f4)(0.f);

#pragma unroll 2
    for (int k = 0; k < 64; k += 4) {
        f4 a[4], w[4];
#pragma unroll
        for (int i = 0; i < 4; ++i) a[i] = *(const f4*)&As[ry + i][k];
#pragma unroll
        for (int kk = 0; kk < 4; ++kk) w[kk] = *(const f4*)&Wt[k + kk][cx];
#pragma unroll
        for (int i = 0; i < 4; ++i) {
#pragma unroll
            for (int kk = 0; kk < 4; ++kk) {
                acc[i] += a[i][kk] * w[kk];
            }
        }
    }
#pragma unroll
    for (int k2 = 64; k2 < 66; ++k2) {
        f4 w = *(const f4*)&Wt[k2][cx];
#pragma unroll
        for (int i = 0; i < 4; ++i) acc[i] += As[ry + i][k2] * w;
    }

#pragma unroll
    for (int i = 0; i < 4; ++i) {
        int grow = row0 + ry + i;
        if (grow >= N) break;
#pragma unroll
        for (int j = 0; j < 4; ++j) {
            int c = c0b + cx + j;
            if (c < OD) U[(size_t)grow * ldU + c] = acc[i][j] + bias[c];
        }
    }
}

// ---------------- segment max, OD=64, lane = channel ----------------
// latency-bound gather: 4-wide edge unroll gives 4 outstanding row loads;
// grid = SEG_BLOCKS(2048) * 4 waves = full chip.

template <bool STATS>
__global__ __launch_bounds__(256)
void segmax64(const float* __restrict__ U, const float* __restrict__ pos,
              const float* __restrict__ W, const int* __restrict__ offs,
              const int* __restrict__ csr, float* __restrict__ out,
              float* __restrict__ partials, int N) {
    int lane = threadIdx.x & 63;
    int wv   = threadIdx.x >> 6;
    int gw   = blockIdx.x * 4 + wv;
    int nw   = gridDim.x * 4;
    float wp0 = W[lane * 66 + 64];
    float wp1 = W[lane * 66 + 65];
    float sum = 0.f, sq = 0.f;
    for (int i = gw; i < N; i += nw) {
        int s0 = offs[i], s1 = offs[i + 1];
        float m = -INFINITY;
        int e = s0;
        for (; e + 4 <= s1; e += 4) {
            int j0 = csr[e], j1 = csr[e + 1], j2 = csr[e + 2], j3 = csr[e + 3];
            float v0 = U[(size_t)j0 * 64 + lane];
            float v1 = U[(size_t)j1 * 64 + lane];
            float v2 = U[(size_t)j2 * 64 + lane];
            float v3 = U[(size_t)j3 * 64 + lane];
            m = fmaxf(m, fmaxf(fmaxf(v0, v1), fmaxf(v2, v3)));
        }
        for (; e < s1; ++e)
            m = fmaxf(m, U[(size_t)csr[e] * 64 + lane]);
        float val = 0.f;
        if (s1 > s0) val = m - (pos[i * 3] * wp0 + pos[i * 3 + 1] * wp1);
        out[(size_t)i * 64 + lane] = val;
        if (STATS) { sum += val; sq += val * val; }
    }
    if (STATS) {
        __shared__ float ls[4][64];
        __shared__ float lq[4][64];
        ls[wv][lane] = sum; lq[wv][lane] = sq;
        __syncthreads();
        if (wv == 0) {
            float s = ls[0][lane] + ls[1][lane] + ls[2][lane] + ls[3][lane];
            float q = lq[0][lane] + lq[1][lane] + lq[2][lane] + lq[3][lane];
            partials[blockIdx.x * 128 + lane]      = s;
            partials[blockIdx.x * 128 + 64 + lane] = q;
        }
    }
}

// ---------------- segment max, OD=101 (cls head), float2/lane ----------------
// U rows padded to LDCLS=102 floats; lane l covers channels 2l, 2l+1 (l<51).
// One wave per node (was a 128-thread group), 4-wide edge unroll.

__global__ __launch_bounds__(256)
void segmax_cls(const float* __restrict__ U, const float* __restrict__ pos,
                const float* __restrict__ W, const int* __restrict__ offs,
                const int* __restrict__ csr, float* __restrict__ out, int N) {
    int lane = threadIdx.x & 63;
    if (lane >= 51) return;               // no barriers below: safe
    int c0 = lane * 2, c1 = c0 + 1;
    int wv = threadIdx.x >> 6;
    int gg = blockIdx.x * 4 + wv;
    int ng = gridDim.x * 4;
    float wa0 = W[c0 * 66 + 64];
    float wa1 = W[c0 * 66 + 65];
    float wb0 = (c1 < NCLS) ? W[c1 * 66 + 64] : 0.f;
    float wb1 = (c1 < NCLS) ? W[c1 * 66 + 65] : 0.f;
    for (int i = gg; i < N; i += ng) {
        int s0 = offs[i], s1 = offs[i + 1];
        f2 m = { -INFINITY, -INFINITY };
        int e = s0;
        for (; e + 4 <= s1; e += 4) {
            int j0 = csr[e], j1 = csr[e + 1], j2 = csr[e + 2], j3 = csr[e + 3];
            f2 v0 = *(const f2*)&U[(size_t)j0 * LDCLS + c0];
            f2 v1 = *(const f2*)&U[(size_t)j1 * LDCLS + c0];
            f2 v2 = *(const f2*)&U[(size_t)j2 * LDCLS + c0];
            f2 v3 = *(const f2*)&U[(size_t)j3 * LDCLS + c0];
            m.x = fmaxf(m.x, fmaxf(fmaxf(v0.x, v1.x), fmaxf(v2.x, v3.x)));
            m.y = fmaxf(m.y, fmaxf(fmaxf(v0.y, v1.y), fmaxf(v2.y, v3.y)));
        }
        for (; e < s1; ++e) {
            f2 v = *(const f2*)&U[(size_t)csr[e] * LDCLS + c0];
            m.x = fmaxf(m.x, v.x);
            m.y = fmaxf(m.y, v.y);
        }
        float p0 = pos[i * 3], p1 = pos[i * 3 + 1];
        float va = 0.f, vb = 0.f;
        if (s1 > s0) {
            va = m.x - (p0 * wa0 + p1 * wa1);
            vb = m.y - (p0 * wb0 + p1 * wb1);
        }
        out[(size_t)i * NCLS + c0] = va;
        if (c1 < NCLS) out[(size_t)i * NCLS + c1] = vb;
    }
}

// ---------------- segment max, small OD (4 / 1) ----------------

__global__ void segmax_small(const float* __restrict__ U, const float* __restrict__ pos,
                             const float* __restrict__ W, const int* __restrict__ offs,
                             const int* __restrict__ csr, float* __restrict__ out,
                             int N, int OD) {
    int t = blockIdx.x * blockDim.x + threadIdx.x;
    if (t >= N * OD) return;
    int i = t / OD;
    int c = t - i * OD;
    int s0 = offs[i], s1 = offs[i + 1];
    float m = -INFINITY;
    int e = s0;
    for (; e + 4 <= s1; e += 4) {
        int j0 = csr[e], j1 = csr[e + 1], j2 = csr[e + 2], j3 = csr[e + 3];
        float v0 = U[(size_t)j0 * OD + c];
        float v1 = U[(size_t)j1 * OD + c];
        float v2 = U[(size_t)j2 * OD + c];
        float v3 = U[(size_t)j3 * OD + c];
        m = fmaxf(m, fmaxf(fmaxf(v0, v1), fmaxf(v2, v3)));
    }
    for (; e < s1; ++e) m = fmaxf(m, U[(size_t)csr[e] * OD + c]);
    float val = 0.f;
    if (s1 > s0) val = m - (pos[i * 3] * W[c * 66 + 64] + pos[i * 3 + 1] * W[c * 66 + 65]);
    out[t] = val;
}

// ---------------- BN finalize: parallel tree reduce ----------------
// 1024 threads: thread t -> channel c=t&63, group g=t>>6; each group sums a
// fixed 128-block slice, then fixed-order 16-way LDS reduce in doubles.

__global__ __launch_bounds__(1024)
void bn_finalize(const float* __restrict__ partials, int N,
                 const float* __restrict__ g, const float* __restrict__ be,
                 float* __restrict__ ab) {
    __shared__ double ls[16][64];
    __shared__ double lq[16][64];
    int t = threadIdx.x;
    int c  = t & 63;
    int gr = t >> 6;          // 0..15
    double s = 0.0, q = 0.0;
#pragma unroll 8
    for (int b = 0; b < SEG_BLOCKS / 16; ++b) {
        int blk = gr * (SEG_BLOCKS / 16) + b;
        s += (double)partials[blk * 128 + c];
        q += (double)partials[blk * 128 + 64 + c];
    }
    ls[gr][c] = s; lq[gr][c] = q;
    __syncthreads();
    if (gr == 0) {
        double ss = 0.0, qq = 0.0;
#pragma unroll
        for (int i = 0; i < 16; ++i) { ss += ls[i][c]; qq += lq[i][c]; }
        double invN = 1.0 / (double)N;
        float m = (float)(ss * invN);
        float v = (float)(qq * invN) - m * m;
        float a = g[c] * rsqrtf(v + 1e-5f);
        ab[c]      = a;
        ab[64 + c] = be[c] - m * a;
    }
}

// ---------------- normalize + relu ----------------

__global__ void norm_relu(const float* __restrict__ s, const float* __restrict__ ab,
                          float* __restrict__ h, int total4) {
    int t = blockIdx.x * blockDim.x + threadIdx.x;
    if (t >= total4) return;
    float4 v = *(const float4*)&s[(size_t)t * 4];
    int c = (t * 4) & 63;
    float4 r;
    r.x = fmaxf(0.f, v.x * ab[c + 0] + ab[64 + c + 0]);
    r.y = fmaxf(0.f, v.y * ab[c + 1] + ab[64 + c + 1]);
    r.z = fmaxf(0.f, v.z * ab[c + 2] + ab[64 + c + 2]);
    r.w = fmaxf(0.f, v.w * ab[c + 3] + ab[64 + c + 3]);
    *(float4*)&h[(size_t)t * 4] = r;
}

// ---------------- launch ----------------

extern "C" void kernel_launch(void* const* d_in, const int* in_sizes, int n_in,
                              void* d_out, int out_size, void* d_ws, size_t ws_size,
                              hipStream_t stream) {
    const float* x       = (const float*)d_in[0];
    const float* pos     = (const float*)d_in[1];
    const int*   ei      = (const int*)d_in[2];
    const float* W_stem  = (const float*)d_in[3];
    const float* b_stem  = (const float*)d_in[4];
    const float* W_conv1 = (const float*)d_in[5];
    const float* b_conv1 = (const float*)d_in[6];
    const float* W_conv2 = (const float*)d_in[7];
    const float* b_conv2 = (const float*)d_in[8];
    const float* W_regr  = (const float*)d_in[9];
    const float* b_regr  = (const float*)d_in[10];
    const float* W_cls   = (const float*)d_in[11];
    const float* b_cls   = (const float*)d_in[12];
    const float* W_obj   = (const float*)d_in[13];
    const float* b_obj   = (const float*)d_in[14];
    const float* g_stem  = (const float*)d_in[15];
    const float* be_stem = (const float*)d_in[16];
    const float* g_conv1 = (const float*)d_in[17];
    const float* be_conv1= (const float*)d_in[18];
    const float* g_conv2 = (const float*)d_in[19];
    const float* be_conv2= (const float*)d_in[20];

    const int N = in_sizes[0] / 64;
    const int E = in_sizes[2] / 2;
    const int* src = ei;
    const int* dst = ei + E;

    // ---- workspace layout (each region 256B aligned) ----
    char* ws = (char*)d_ws;
    size_t off = 0;
    auto carve = [&](size_t bytes) -> char* {
        char* p = ws + off;
        off += (bytes + 255) & ~(size_t)255;
        return p;
    };
    int*   counts   = (int*)carve((size_t)(N + 1) * 4);
    int*   offs     = (int*)carve((size_t)(N + 1) * 4);
    int*   wp       = (int*)carve((size_t)N * 4);
    int*   csr      = (int*)carve((size_t)E * 4);
    float* bufA     = (float*)carve((size_t)N * 64 * 4);   // U_stem -> h ; (with bufB) aliased by U_cls
    float* bufB     = (float*)carve((size_t)N * 64 * 4);   // s_stem -> s1 -> s2
    float* bufC     = (float*)carve((size_t)N * 64 * 4);   // U1 -> x1
    float* bufD     = (float*)carve((size_t)N * 64 * 4);   // U2 -> x2
    float* uSmall   = (float*)carve((size_t)N * 5 * 4);    // U_regr (N*4) + U_obj (N*1)
    float* partials = (float*)carve((size_t)SEG_BLOCKS * 128 * 4);
    float* ab       = (float*)carve(128 * 4);
    float* uCls     = bufA;            // N*LDCLS floats fit in bufA+bufB (contiguous, 40.8<=51.2MB)
    float* uRegr    = uSmall;
    float* uObj     = uSmall + (size_t)N * 4;

    float* out_cls = (float*)d_out;                       // N x 101
    float* out_reg = out_cls + (size_t)N * NCLS;          // N x 4
    float* out_obj = out_reg + (size_t)N * 4;             // N x 1

    const int eg = (E + 255) / 256;
    const dim3 blk(256);

    // ---- CSR build ----
    hipMemsetAsync(counts, 0, (size_t)(N + 1) * 4, stream);
    count_kernel<<<eg, blk, 0, stream>>>(dst, counts, E);
    scan_kernel<<<1, 1024, 0, stream>>>(counts, offs, wp, N);
    fill_kernel<<<eg, blk, 0, stream>>>(src, dst, wp, csr, E);

    const int ng64 = (N + 63) / 64;
    const int nr4  = (N * 64 / 4 + 255) / 256;

    // ---- stem ----
    gemm66<<<dim3(ng64, 1), blk, 0, stream>>>(x, pos, W_stem, b_stem, bufA, N, 64, 64);
    segmax64<true><<<SEG_BLOCKS, blk, 0, stream>>>(bufA, pos, W_stem, offs, csr, bufB, partials, N);
    bn_finalize<<<1, 1024, 0, stream>>>(partials, N, g_stem, be_stem, ab);
    norm_relu<<<nr4, blk, 0, stream>>>(bufB, ab, bufA, N * 64 / 4);           // h = bufA

    // ---- conv1 / conv2 ----
    gemm66<<<dim3(ng64, 1), blk, 0, stream>>>(bufA, pos, W_conv1, b_conv1, bufC, N, 64, 64);
    gemm66<<<dim3(ng64, 1), blk, 0, stream>>>(bufA, pos, W_conv2, b_conv2, bufD, N, 64, 64);

    segmax64<true><<<SEG_BLOCKS, blk, 0, stream>>>(bufC, pos, W_conv1, offs, csr, bufB, partials, N);
    bn_finalize<<<1, 1024, 0, stream>>>(partials, N, g_conv1, be_conv1, ab);
    norm_relu<<<nr4, blk, 0, stream>>>(bufB, ab, bufC, N * 64 / 4);           // x1 = bufC

    segmax64<true><<<SEG_BLOCKS, blk, 0, stream>>>(bufD, pos, W_conv2, offs, csr, bufB, partials, N);
    bn_finalize<<<1, 1024, 0, stream>>>(partials, N, g_conv2, be_conv2, ab);
    norm_relu<<<nr4, blk, 0, stream>>>(bufB, ab, bufD, N * 64 / 4);           // x2 = bufD

    // ---- heads ----
    gemm66<<<dim3(ng64, 1), blk, 0, stream>>>(bufC, pos, W_regr, b_regr, uRegr, N, 4, 4);
    gemm66<<<dim3(ng64, 1), blk, 0, stream>>>(bufC, pos, W_obj,  b_obj,  uObj,  N, 1, 1);
    gemm66<<<dim3(ng64, 2), blk, 0, stream>>>(bufD, pos, W_cls,  b_cls,  uCls,  N, NCLS, LDCLS);

    segmax_cls<<<SEG_BLOCKS, blk, 0, stream>>>(uCls, pos, W_cls, offs, csr, out_cls, N);
    segmax_small<<<(N * 4 + 255) / 256, blk, 0, stream>>>(uRegr, pos, W_regr, offs, csr, out_reg, N, 4);
    segmax_small<<<(N + 255) / 256, blk, 0, stream>>>(uObj, pos, W_obj, offs, csr, out_obj, N, 1);
}

// Round 5
// 717.817 us; speedup vs baseline: 7.3098x; 1.3052x over previous
//
#include <hip/hip_runtime.h>
#include <math.h>

#define C64 64
#define CIN 66
#define NCLS 101
#define LDCLS 102          // padded row stride for U_cls (float2-aligned per lane)
#define SEG_BLOCKS 2048    // fixed grid for segmax kernels (deterministic stats slots)
#define SCAN_BLOCKS 256

typedef float f4 __attribute__((ext_vector_type(4)));
typedef float f2 __attribute__((ext_vector_type(2)));

// ---------------- CSR build ----------------

__global__ void count_kernel(const int* __restrict__ dst, int* __restrict__ counts, int E) {
    int e = blockIdx.x * blockDim.x + threadIdx.x;
    if (e < E) atomicAdd(&counts[dst[e]], 1);
}

// phase 1: per-block totals over contiguous regions
__global__ __launch_bounds__(256)
void partial_sum_kernel(const int* __restrict__ counts, int* __restrict__ blockSums, int N) {
    __shared__ int red[256];
    int per_block = (N + SCAN_BLOCKS - 1) / SCAN_BLOCKS;
    int lo = blockIdx.x * per_block;
    int hi = lo + per_block; if (hi > N) hi = N;
    int s = 0;
    for (int i = lo + threadIdx.x; i < hi; i += 256) s += counts[i];
    red[threadIdx.x] = s;
    __syncthreads();
    for (int off = 128; off > 0; off >>= 1) {
        if (threadIdx.x < off) red[threadIdx.x] += red[threadIdx.x + off];
        __syncthreads();
    }
    if (threadIdx.x == 0) blockSums[blockIdx.x] = red[0];
}

// phase 2: exclusive scan of the 256 block totals; writes offs[N] = grand total
__global__ __launch_bounds__(256)
void scan_sums_kernel(int* __restrict__ blockSums, int* __restrict__ offs, int N) {
    __shared__ int buf[2][SCAN_BLOCKS];
    int t = threadIdx.x;
    int v = blockSums[t];
    buf[0][t] = v;
    __syncthreads();
    int cur = 0;
#pragma unroll
    for (int off = 1; off < SCAN_BLOCKS; off <<= 1) {
        int nv = buf[cur][t];
        if (t >= off) nv += buf[cur][t - off];
        buf[cur ^ 1][t] = nv;
        cur ^= 1;
        __syncthreads();
    }
    // buf[cur][t] = inclusive scan
    blockSums[t] = buf[cur][t] - v;            // exclusive
    if (t == SCAN_BLOCKS - 1) offs[N] = buf[cur][t];
}

// phase 3: per-block local scan + base, writes offs and wp
__global__ __launch_bounds__(256)
void scan_apply_kernel(const int* __restrict__ counts, const int* __restrict__ blockSums,
                       int* __restrict__ offs, int* __restrict__ wp, int N) {
    __shared__ int buf[2][256];
    int per_block = (N + SCAN_BLOCKS - 1) / SCAN_BLOCKS;
    int stc = (per_block + 255) / 256;         // per-thread contiguous sub-chunk
    int lo = blockIdx.x * per_block;
    int hi = lo + per_block; if (hi > N) hi = N;
    int t = threadIdx.x;
    int tlo = lo + t * stc;
    int thi = tlo + stc; if (thi > hi) thi = hi;
    int s = 0;
    for (int i = tlo; i < thi; ++i) s += counts[i];
    buf[0][t] = s;
    __syncthreads();
    int cur = 0;
#pragma unroll
    for (int off = 1; off < 256; off <<= 1) {
        int nv = buf[cur][t];
        if (t >= off) nv += buf[cur][t - off];
        buf[cur ^ 1][t] = nv;
        cur ^= 1;
        __syncthreads();
    }
    int run = blockSums[blockIdx.x] + buf[cur][t] - s;   // exclusive base for this thread
    for (int i = tlo; i < thi; ++i) {
        offs[i] = run; wp[i] = run; run += counts[i];
    }
}

__global__ void fill_kernel(const int* __restrict__ src, const int* __restrict__ dst,
                            int* __restrict__ wp, int* __restrict__ csr, int E) {
    int e = blockIdx.x * blockDim.x + threadIdx.x;
    if (e < E) {
        int p = atomicAdd(&wp[dst[e]], 1);
        csr[p] = src[e];
    }
}

// ---------------- node-side GEMM: U = [feat|pos2] @ W^T + b ----------------
// feat: N x 64, pos: N x 3 (cols 0,1 used), W: OD x 66, bias: OD, U: N x ldU

__global__ __launch_bounds__(256)
void gemm66(const float* __restrict__ feat, const float* __restrict__ pos,
            const float* __restrict__ W, const float* __restrict__ bias,
            float* __restrict__ U, int N, int OD, int ldU) {
    __shared__ __attribute__((aligned(16))) float As[64][68];   // [row][k]
    __shared__ __attribute__((aligned(16))) float Wt[66][68];   // [k][col] (transposed W)
    int row0 = blockIdx.x * 64;
    int c0b  = blockIdx.y * 64;
    int tid  = threadIdx.x;

    for (int idx = tid; idx < 64 * 66; idx += 256) {
        int r = idx / 66, k = idx - r * 66;
        int grow = row0 + r;
        float v = 0.f;
        if (grow < N) v = (k < 64) ? feat[(size_t)grow * 64 + k] : pos[(size_t)grow * 3 + (k - 64)];
        As[r][k] = v;
    }
    for (int idx = tid; idx < 64 * 66; idx += 256) {
        int c = idx / 66, k = idx - c * 66;
        float v = 0.f;
        if (c0b + c < OD) v = W[(size_t)(c0b + c) * 66 + k];
        Wt[k][c] = v;
    }
    __syncthreads();

    const int cx = (tid & 15) * 4;   // col offset in tile
    const int ry = (tid >> 4) * 4;   // row offset in tile

    f4 acc[4];
#pragma unroll
    for (int i = 0; i < 4; ++i) acc[i] = (f4)(0.f);

#pragma unroll 2
    for (int k = 0; k < 64; k += 4) {
        f4 a[4], w[4];
#pragma unroll
        for (int i = 0; i < 4; ++i) a[i] = *(const f4*)&As[ry + i][k];
#pragma unroll
        for (int kk = 0; kk < 4; ++kk) w[kk] = *(const f4*)&Wt[k + kk][cx];
#pragma unroll
        for (int i = 0; i < 4; ++i) {
#pragma unroll
            for (int kk = 0; kk < 4; ++kk) {
                acc[i] += a[i][kk] * w[kk];
            }
        }
    }
#pragma unroll
    for (int k2 = 64; k2 < 66; ++k2) {
        f4 w = *(const f4*)&Wt[k2][cx];
#pragma unroll
        for (int i = 0; i < 4; ++i) acc[i] += As[ry + i][k2] * w;
    }

#pragma unroll
    for (int i = 0; i < 4; ++i) {
        int grow = row0 + ry + i;
        if (grow >= N) break;
#pragma unroll
        for (int j = 0; j < 4; ++j) {
            int c = c0b + cx + j;
            if (c < OD) U[(size_t)grow * ldU + c] = acc[i][j] + bias[c];
        }
    }
}

// ---------------- segment max, OD=64, lane = channel ----------------
// latency-bound gather: 4-wide edge unroll gives 4 outstanding row loads;
// grid = SEG_BLOCKS(2048) * 4 waves = full chip.

template <bool STATS>
__global__ __launch_bounds__(256)
void segmax64(const float* __restrict__ U, const float* __restrict__ pos,
              const float* __restrict__ W, const int* __restrict__ offs,
              const int* __restrict__ csr, float* __restrict__ out,
              float* __restrict__ partials, int N) {
    int lane = threadIdx.x & 63;
    int wv   = threadIdx.x >> 6;
    int gw   = blockIdx.x * 4 + wv;
    int nw   = gridDim.x * 4;
    float wp0 = W[lane * 66 + 64];
    float wp1 = W[lane * 66 + 65];
    float sum = 0.f, sq = 0.f;
    for (int i = gw; i < N; i += nw) {
        int s0 = offs[i], s1 = offs[i + 1];
        float m = -INFINITY;
        int e = s0;
        for (; e + 4 <= s1; e += 4) {
            int j0 = csr[e], j1 = csr[e + 1], j2 = csr[e + 2], j3 = csr[e + 3];
            float v0 = U[(size_t)j0 * 64 + lane];
            float v1 = U[(size_t)j1 * 64 + lane];
            float v2 = U[(size_t)j2 * 64 + lane];
            float v3 = U[(size_t)j3 * 64 + lane];
            m = fmaxf(m, fmaxf(fmaxf(v0, v1), fmaxf(v2, v3)));
        }
        for (; e < s1; ++e)
            m = fmaxf(m, U[(size_t)csr[e] * 64 + lane]);
        float val = 0.f;
        if (s1 > s0) val = m - (pos[i * 3] * wp0 + pos[i * 3 + 1] * wp1);
        out[(size_t)i * 64 + lane] = val;
        if (STATS) { sum += val; sq += val * val; }
    }
    if (STATS) {
        __shared__ float ls[4][64];
        __shared__ float lq[4][64];
        ls[wv][lane] = sum; lq[wv][lane] = sq;
        __syncthreads();
        if (wv == 0) {
            float s = ls[0][lane] + ls[1][lane] + ls[2][lane] + ls[3][lane];
            float q = lq[0][lane] + lq[1][lane] + lq[2][lane] + lq[3][lane];
            partials[blockIdx.x * 128 + lane]      = s;
            partials[blockIdx.x * 128 + 64 + lane] = q;
        }
    }
}

// ---------------- segment max, OD=101 (cls head), float2/lane ----------------
// U rows padded to LDCLS=102 floats; lane l covers channels 2l, 2l+1 (l<51).

__global__ __launch_bounds__(256)
void segmax_cls(const float* __restrict__ U, const float* __restrict__ pos,
                const float* __restrict__ W, const int* __restrict__ offs,
                const int* __restrict__ csr, float* __restrict__ out, int N) {
    int lane = threadIdx.x & 63;
    if (lane >= 51) return;               // no barriers below: safe
    int c0 = lane * 2, c1 = c0 + 1;
    int wv = threadIdx.x >> 6;
    int gg = blockIdx.x * 4 + wv;
    int ng = gridDim.x * 4;
    float wa0 = W[c0 * 66 + 64];
    float wa1 = W[c0 * 66 + 65];
    float wb0 = (c1 < NCLS) ? W[c1 * 66 + 64] : 0.f;
    float wb1 = (c1 < NCLS) ? W[c1 * 66 + 65] : 0.f;
    for (int i = gg; i < N; i += ng) {
        int s0 = offs[i], s1 = offs[i + 1];
        f2 m = { -INFINITY, -INFINITY };
        int e = s0;
        for (; e + 4 <= s1; e += 4) {
            int j0 = csr[e], j1 = csr[e + 1], j2 = csr[e + 2], j3 = csr[e + 3];
            f2 v0 = *(const f2*)&U[(size_t)j0 * LDCLS + c0];
            f2 v1 = *(const f2*)&U[(size_t)j1 * LDCLS + c0];
            f2 v2 = *(const f2*)&U[(size_t)j2 * LDCLS + c0];
            f2 v3 = *(const f2*)&U[(size_t)j3 * LDCLS + c0];
            m.x = fmaxf(m.x, fmaxf(fmaxf(v0.x, v1.x), fmaxf(v2.x, v3.x)));
            m.y = fmaxf(m.y, fmaxf(fmaxf(v0.y, v1.y), fmaxf(v2.y, v3.y)));
        }
        for (; e < s1; ++e) {
            f2 v = *(const f2*)&U[(size_t)csr[e] * LDCLS + c0];
            m.x = fmaxf(m.x, v.x);
            m.y = fmaxf(m.y, v.y);
        }
        float p0 = pos[i * 3], p1 = pos[i * 3 + 1];
        float va = 0.f, vb = 0.f;
        if (s1 > s0) {
            va = m.x - (p0 * wa0 + p1 * wa1);
            vb = m.y - (p0 * wb0 + p1 * wb1);
        }
        out[(size_t)i * NCLS + c0] = va;
        if (c1 < NCLS) out[(size_t)i * NCLS + c1] = vb;
    }
}

// ---------------- segment max, small OD (4 / 1) ----------------

__global__ void segmax_small(const float* __restrict__ U, const float* __restrict__ pos,
                             const float* __restrict__ W, const int* __restrict__ offs,
                             const int* __restrict__ csr, float* __restrict__ out,
                             int N, int OD) {
    int t = blockIdx.x * blockDim.x + threadIdx.x;
    if (t >= N * OD) return;
    int i = t / OD;
    int c = t - i * OD;
    int s0 = offs[i], s1 = offs[i + 1];
    float m = -INFINITY;
    int e = s0;
    for (; e + 4 <= s1; e += 4) {
        int j0 = csr[e], j1 = csr[e + 1], j2 = csr[e + 2], j3 = csr[e + 3];
        float v0 = U[(size_t)j0 * OD + c];
        float v1 = U[(size_t)j1 * OD + c];
        float v2 = U[(size_t)j2 * OD + c];
        float v3 = U[(size_t)j3 * OD + c];
        m = fmaxf(m, fmaxf(fmaxf(v0, v1), fmaxf(v2, v3)));
    }
    for (; e < s1; ++e) m = fmaxf(m, U[(size_t)csr[e] * OD + c]);
    float val = 0.f;
    if (s1 > s0) val = m - (pos[i * 3] * W[c * 66 + 64] + pos[i * 3 + 1] * W[c * 66 + 65]);
    out[t] = val;
}

// ---------------- BN finalize: parallel tree reduce ----------------

__global__ __launch_bounds__(1024)
void bn_finalize(const float* __restrict__ partials, int N,
                 const float* __restrict__ g, const float* __restrict__ be,
                 float* __restrict__ ab) {
    __shared__ double ls[16][64];
    __shared__ double lq[16][64];
    int t = threadIdx.x;
    int c  = t & 63;
    int gr = t >> 6;          // 0..15
    double s = 0.0, q = 0.0;
#pragma unroll 8
    for (int b = 0; b < SEG_BLOCKS / 16; ++b) {
        int blk = gr * (SEG_BLOCKS / 16) + b;
        s += (double)partials[blk * 128 + c];
        q += (double)partials[blk * 128 + 64 + c];
    }
    ls[gr][c] = s; lq[gr][c] = q;
    __syncthreads();
    if (gr == 0) {
        double ss = 0.0, qq = 0.0;
#pragma unroll
        for (int i = 0; i < 16; ++i) { ss += ls[i][c]; qq += lq[i][c]; }
        double invN = 1.0 / (double)N;
        float m = (float)(ss * invN);
        float v = (float)(qq * invN) - m * m;
        float a = g[c] * rsqrtf(v + 1e-5f);
        ab[c]      = a;
        ab[64 + c] = be[c] - m * a;
    }
}

// ---------------- normalize + relu ----------------

__global__ void norm_relu(const float* __restrict__ s, const float* __restrict__ ab,
                          float* __restrict__ h, int total4) {
    int t = blockIdx.x * blockDim.x + threadIdx.x;
    if (t >= total4) return;
    float4 v = *(const float4*)&s[(size_t)t * 4];
    int c = (t * 4) & 63;
    float4 r;
    r.x = fmaxf(0.f, v.x * ab[c + 0] + ab[64 + c + 0]);
    r.y = fmaxf(0.f, v.y * ab[c + 1] + ab[64 + c + 1]);
    r.z = fmaxf(0.f, v.z * ab[c + 2] + ab[64 + c + 2]);
    r.w = fmaxf(0.f, v.w * ab[c + 3] + ab[64 + c + 3]);
    *(float4*)&h[(size_t)t * 4] = r;
}

// ---------------- launch ----------------

extern "C" void kernel_launch(void* const* d_in, const int* in_sizes, int n_in,
                              void* d_out, int out_size, void* d_ws, size_t ws_size,
                              hipStream_t stream) {
    const float* x       = (const float*)d_in[0];
    const float* pos     = (const float*)d_in[1];
    const int*   ei      = (const int*)d_in[2];
    const float* W_stem  = (const float*)d_in[3];
    const float* b_stem  = (const float*)d_in[4];
    const float* W_conv1 = (const float*)d_in[5];
    const float* b_conv1 = (const float*)d_in[6];
    const float* W_conv2 = (const float*)d_in[7];
    const float* b_conv2 = (const float*)d_in[8];
    const float* W_regr  = (const float*)d_in[9];
    const float* b_regr  = (const float*)d_in[10];
    const float* W_cls   = (const float*)d_in[11];
    const float* b_cls   = (const float*)d_in[12];
    const float* W_obj   = (const float*)d_in[13];
    const float* b_obj   = (const float*)d_in[14];
    const float* g_stem  = (const float*)d_in[15];
    const float* be_stem = (const float*)d_in[16];
    const float* g_conv1 = (const float*)d_in[17];
    const float* be_conv1= (const float*)d_in[18];
    const float* g_conv2 = (const float*)d_in[19];
    const float* be_conv2= (const float*)d_in[20];

    const int N = in_sizes[0] / 64;
    const int E = in_sizes[2] / 2;
    const int* src = ei;
    const int* dst = ei + E;

    // ---- workspace layout (each region 256B aligned) ----
    char* ws = (char*)d_ws;
    size_t off = 0;
    auto carve = [&](size_t bytes) -> char* {
        char* p = ws + off;
        off += (bytes + 255) & ~(size_t)255;
        return p;
    };
    int*   counts   = (int*)carve((size_t)(N + 1) * 4);
    int*   offs     = (int*)carve((size_t)(N + 1) * 4);
    int*   wp       = (int*)carve((size_t)N * 4);
    int*   csr      = (int*)carve((size_t)E * 4);
    int*   blockSums= (int*)carve((size_t)SCAN_BLOCKS * 4);
    float* bufA     = (float*)carve((size_t)N * 64 * 4);   // U_stem -> h ; (with bufB) aliased by U_cls
    float* bufB     = (float*)carve((size_t)N * 64 * 4);   // s_stem -> s1 -> s2
    float* bufC     = (float*)carve((size_t)N * 64 * 4);   // U1 -> x1
    float* bufD     = (float*)carve((size_t)N * 64 * 4);   // U2 -> x2
    float* uSmall   = (float*)carve((size_t)N * 5 * 4);    // U_regr (N*4) + U_obj (N*1)
    float* partials = (float*)carve((size_t)SEG_BLOCKS * 128 * 4);
    float* ab       = (float*)carve(128 * 4);
    float* uCls     = bufA;            // N*LDCLS floats fit in bufA+bufB (contiguous, 40.8<=51.2MB)
    float* uRegr    = uSmall;
    float* uObj     = uSmall + (size_t)N * 4;

    float* out_cls = (float*)d_out;                       // N x 101
    float* out_reg = out_cls + (size_t)N * NCLS;          // N x 4
    float* out_obj = out_reg + (size_t)N * 4;             // N x 1

    const int eg = (E + 255) / 256;
    const dim3 blk(256);

    // ---- CSR build ----
    hipMemsetAsync(counts, 0, (size_t)(N + 1) * 4, stream);
    count_kernel<<<eg, blk, 0, stream>>>(dst, counts, E);
    partial_sum_kernel<<<SCAN_BLOCKS, blk, 0, stream>>>(counts, blockSums, N);
    scan_sums_kernel<<<1, SCAN_BLOCKS, 0, stream>>>(blockSums, offs, N);
    scan_apply_kernel<<<SCAN_BLOCKS, blk, 0, stream>>>(counts, blockSums, offs, wp, N);
    fill_kernel<<<eg, blk, 0, stream>>>(src, dst, wp, csr, E);

    const int ng64 = (N + 63) / 64;
    const int nr4  = (N * 64 / 4 + 255) / 256;

    // ---- stem ----
    gemm66<<<dim3(ng64, 1), blk, 0, stream>>>(x, pos, W_stem, b_stem, bufA, N, 64, 64);
    segmax64<true><<<SEG_BLOCKS, blk, 0, stream>>>(bufA, pos, W_stem, offs, csr, bufB, partials, N);
    bn_finalize<<<1, 1024, 0, stream>>>(partials, N, g_stem, be_stem, ab);
    norm_relu<<<nr4, blk, 0, stream>>>(bufB, ab, bufA, N * 64 / 4);           // h = bufA

    // ---- conv1 / conv2 ----
    gemm66<<<dim3(ng64, 1), blk, 0, stream>>>(bufA, pos, W_conv1, b_conv1, bufC, N, 64, 64);
    gemm66<<<dim3(ng64, 1), blk, 0, stream>>>(bufA, pos, W_conv2, b_conv2, bufD, N, 64, 64);

    segmax64<true><<<SEG_BLOCKS, blk, 0, stream>>>(bufC, pos, W_conv1, offs, csr, bufB, partials, N);
    bn_finalize<<<1, 1024, 0, stream>>>(partials, N, g_conv1, be_conv1, ab);
    norm_relu<<<nr4, blk, 0, stream>>>(bufB, ab, bufC, N * 64 / 4);           // x1 = bufC

    segmax64<true><<<SEG_BLOCKS, blk, 0, stream>>>(bufD, pos, W_conv2, offs, csr, bufB, partials, N);
    bn_finalize<<<1, 1024, 0, stream>>>(partials, N, g_conv2, be_conv2, ab);
    norm_relu<<<nr4, blk, 0, stream>>>(bufB, ab, bufD, N * 64 / 4);           // x2 = bufD

    // ---- heads ----
    gemm66<<<dim3(ng64, 1), blk, 0, stream>>>(bufC, pos, W_regr, b_regr, uRegr, N, 4, 4);
    gemm66<<<dim3(ng64, 1), blk, 0, stream>>>(bufC, pos, W_obj,  b_obj,  uObj,  N, 1, 1);
    gemm66<<<dim3(ng64, 2), blk, 0, stream>>>(bufD, pos, W_cls,  b_cls,  uCls,  N, NCLS, LDCLS);

    segmax_cls<<<SEG_BLOCKS, blk, 0, stream>>>(uCls, pos, W_cls, offs, csr, out_cls, N);
    segmax_small<<<(N * 4 + 255) / 256, blk, 0, stream>>>(uRegr, pos, W_regr, offs, csr, out_reg, N, 4);
    segmax_small<<<(N + 255) / 256, blk, 0, stream>>>(uObj, pos, W_obj, offs, csr, out_obj, N, 1);
}

// Round 6
// 545.828 us; speedup vs baseline: 9.6131x; 1.3151x over previous
//
#include <hip/hip_runtime.h>
#include <math.h>

#define C64 64
#define CIN 66
#define NCLS 101
#define LDCLS 102          // padded bf16 row stride for U_cls
#define SEG_BLOCKS 2048    // fixed grid for segmax kernels (deterministic stats slots)
#define SCAN_BLOCKS 256

typedef float f4 __attribute__((ext_vector_type(4)));
typedef float f2 __attribute__((ext_vector_type(2)));

// bf16 helpers (RNE pack, shift expand)
__device__ __forceinline__ unsigned short f2bf(float f) {
    unsigned int u = __float_as_uint(f);
    u += 0x7fffu + ((u >> 16) & 1u);
    return (unsigned short)(u >> 16);
}
__device__ __forceinline__ f2 bf2(unsigned int u) {
    f2 r;
    r.x = __uint_as_float(u << 16);
    r.y = __uint_as_float(u & 0xffff0000u);
    return r;
}

// ---------------- CSR build ----------------

__global__ void count_kernel(const int* __restrict__ dst, int* __restrict__ counts, int E) {
    int e = blockIdx.x * blockDim.x + threadIdx.x;
    if (e < E) atomicAdd(&counts[dst[e]], 1);
}

__global__ __launch_bounds__(256)
void partial_sum_kernel(const int* __restrict__ counts, int* __restrict__ blockSums, int N) {
    __shared__ int red[256];
    int per_block = (N + SCAN_BLOCKS - 1) / SCAN_BLOCKS;
    int lo = blockIdx.x * per_block;
    int hi = lo + per_block; if (hi > N) hi = N;
    int s = 0;
    for (int i = lo + threadIdx.x; i < hi; i += 256) s += counts[i];
    red[threadIdx.x] = s;
    __syncthreads();
    for (int off = 128; off > 0; off >>= 1) {
        if (threadIdx.x < off) red[threadIdx.x] += red[threadIdx.x + off];
        __syncthreads();
    }
    if (threadIdx.x == 0) blockSums[blockIdx.x] = red[0];
}

__global__ __launch_bounds__(256)
void scan_sums_kernel(int* __restrict__ blockSums, int* __restrict__ offs, int N) {
    __shared__ int buf[2][SCAN_BLOCKS];
    int t = threadIdx.x;
    int v = blockSums[t];
    buf[0][t] = v;
    __syncthreads();
    int cur = 0;
#pragma unroll
    for (int off = 1; off < SCAN_BLOCKS; off <<= 1) {
        int nv = buf[cur][t];
        if (t >= off) nv += buf[cur][t - off];
        buf[cur ^ 1][t] = nv;
        cur ^= 1;
        __syncthreads();
    }
    blockSums[t] = buf[cur][t] - v;            // exclusive
    if (t == SCAN_BLOCKS - 1) offs[N] = buf[cur][t];
}

__global__ __launch_bounds__(256)
void scan_apply_kernel(const int* __restrict__ counts, const int* __restrict__ blockSums,
                       int* __restrict__ offs, int* __restrict__ wp, int N) {
    __shared__ int buf[2][256];
    int per_block = (N + SCAN_BLOCKS - 1) / SCAN_BLOCKS;
    int stc = (per_block + 255) / 256;
    int lo = blockIdx.x * per_block;
    int hi = lo + per_block; if (hi > N) hi = N;
    int t = threadIdx.x;
    int tlo = lo + t * stc;
    int thi = tlo + stc; if (thi > hi) thi = hi;
    int s = 0;
    for (int i = tlo; i < thi; ++i) s += counts[i];
    buf[0][t] = s;
    __syncthreads();
    int cur = 0;
#pragma unroll
    for (int off = 1; off < 256; off <<= 1) {
        int nv = buf[cur][t];
        if (t >= off) nv += buf[cur][t - off];
        buf[cur ^ 1][t] = nv;
        cur ^= 1;
        __syncthreads();
    }
    int run = blockSums[blockIdx.x] + buf[cur][t] - s;
    for (int i = tlo; i < thi; ++i) {
        offs[i] = run; wp[i] = run; run += counts[i];
    }
}

__global__ void fill_kernel(const int* __restrict__ src, const int* __restrict__ dst,
                            int* __restrict__ wp, int* __restrict__ csr, int E) {
    int e = blockIdx.x * blockDim.x + threadIdx.x;
    if (e < E) {
        int p = atomicAdd(&wp[dst[e]], 1);
        csr[p] = src[e];
    }
}

// ---------------- GEMM helpers ----------------
// stage A tile: optional fused BN+ReLU on the 64 feature channels (ab != nullptr)

__device__ __forceinline__ void stage_A(float (*As)[68], const float* __restrict__ feat,
                                        const float* __restrict__ pos, const float* __restrict__ ab,
                                        int row0, int N, int tid) {
    for (int idx = tid; idx < 64 * 66; idx += 256) {
        int r = idx / 66, k = idx - r * 66;
        int grow = row0 + r;
        float v = 0.f;
        if (grow < N) {
            if (k < 64) {
                v = feat[(size_t)grow * 64 + k];
                if (ab) v = fmaxf(0.f, v * ab[k] + ab[64 + k]);
            } else {
                v = pos[(size_t)grow * 3 + (k - 64)];
            }
        }
        As[r][k] = v;
    }
}

// general GEMM -> bf16 output (used for stem U and cls U)
__global__ __launch_bounds__(256)
void gemm_bf16(const float* __restrict__ feat, const float* __restrict__ pos,
               const float* __restrict__ W, const float* __restrict__ bias,
               const float* __restrict__ ab, unsigned short* __restrict__ U,
               int N, int OD, int ldU) {
    __shared__ __attribute__((aligned(16))) float As[64][68];
    __shared__ __attribute__((aligned(16))) float Wt[66][68];
    int row0 = blockIdx.x * 64;
    int c0b  = blockIdx.y * 64;
    int tid  = threadIdx.x;

    stage_A(As, feat, pos, ab, row0, N, tid);
    for (int idx = tid; idx < 64 * 66; idx += 256) {
        int c = idx / 66, k = idx - c * 66;
        float v = 0.f;
        if (c0b + c < OD) v = W[(size_t)(c0b + c) * 66 + k];
        Wt[k][c] = v;
    }
    __syncthreads();

    const int cx = (tid & 15) * 4;
    const int ry = (tid >> 4) * 4;

    f4 acc[4];
#pragma unroll
    for (int i = 0; i < 4; ++i) acc[i] = (f4)(0.f);

#pragma unroll 2
    for (int k = 0; k < 64; k += 4) {
        f4 a[4], w[4];
#pragma unroll
        for (int i = 0; i < 4; ++i) a[i] = *(const f4*)&As[ry + i][k];
#pragma unroll
        for (int kk = 0; kk < 4; ++kk) w[kk] = *(const f4*)&Wt[k + kk][cx];
#pragma unroll
        for (int i = 0; i < 4; ++i)
#pragma unroll
            for (int kk = 0; kk < 4; ++kk) acc[i] += a[i][kk] * w[kk];
    }
#pragma unroll
    for (int k2 = 64; k2 < 66; ++k2) {
        f4 w = *(const f4*)&Wt[k2][cx];
#pragma unroll
        for (int i = 0; i < 4; ++i) acc[i] += As[ry + i][k2] * w;
    }

    int c = c0b + cx;
#pragma unroll
    for (int i = 0; i < 4; ++i) {
        int grow = row0 + ry + i;
        if (grow >= N) break;
        size_t base = (size_t)grow * ldU + c;
        if (c + 3 < OD) {
            unsigned int lo = (unsigned int)f2bf(acc[i][0] + bias[c + 0])
                            | ((unsigned int)f2bf(acc[i][1] + bias[c + 1]) << 16);
            unsigned int hi = (unsigned int)f2bf(acc[i][2] + bias[c + 2])
                            | ((unsigned int)f2bf(acc[i][3] + bias[c + 3]) << 16);
            *(unsigned int*)&U[base]     = lo;
            *(unsigned int*)&U[base + 2] = hi;
        } else {
#pragma unroll
            for (int j = 0; j < 4; ++j)
                if (c + j < OD) U[base + j] = f2bf(acc[i][j] + bias[c + j]);
        }
    }
}

// dual GEMM (conv1 + conv2 share the normalized input tile); two sequential
// K-passes keep live VGPRs ~64 (round-1 lesson: avoid register blowup)
__global__ __launch_bounds__(256)
void gemm_dual_bf16(const float* __restrict__ s, const float* __restrict__ pos,
                    const float* __restrict__ W1, const float* __restrict__ b1,
                    const float* __restrict__ W2, const float* __restrict__ b2,
                    const float* __restrict__ ab,
                    unsigned short* __restrict__ U1, unsigned short* __restrict__ U2, int N) {
    __shared__ __attribute__((aligned(16))) float As[64][68];
    __shared__ __attribute__((aligned(16))) float Wt1[66][68];
    __shared__ __attribute__((aligned(16))) float Wt2[66][68];
    int row0 = blockIdx.x * 64;
    int tid  = threadIdx.x;

    stage_A(As, s, pos, ab, row0, N, tid);
    for (int idx = tid; idx < 64 * 66; idx += 256) {
        int c = idx / 66, k = idx - c * 66;
        Wt1[k][c] = W1[(size_t)c * 66 + k];
        Wt2[k][c] = W2[(size_t)c * 66 + k];
    }
    __syncthreads();

    const int cx = (tid & 15) * 4;
    const int ry = (tid >> 4) * 4;

    // pass 1: W1
    f4 acc1[4];
#pragma unroll
    for (int i = 0; i < 4; ++i) acc1[i] = (f4)(0.f);
#pragma unroll 2
    for (int k = 0; k < 64; k += 4) {
        f4 a[4], w[4];
#pragma unroll
        for (int i = 0; i < 4; ++i) a[i] = *(const f4*)&As[ry + i][k];
#pragma unroll
        for (int kk = 0; kk < 4; ++kk) w[kk] = *(const f4*)&Wt1[k + kk][cx];
#pragma unroll
        for (int i = 0; i < 4; ++i)
#pragma unroll
            for (int kk = 0; kk < 4; ++kk) acc1[i] += a[i][kk] * w[kk];
    }
#pragma unroll
    for (int k2 = 64; k2 < 66; ++k2) {
        f4 w = *(const f4*)&Wt1[k2][cx];
#pragma unroll
        for (int i = 0; i < 4; ++i) acc1[i] += As[ry + i][k2] * w;
    }
#pragma unroll
    for (int i = 0; i < 4; ++i) {
        int grow = row0 + ry + i;
        if (grow >= N) break;
        size_t base = (size_t)grow * 64 + cx;
        unsigned int lo = (unsigned int)f2bf(acc1[i][0] + b1[cx + 0])
                        | ((unsigned int)f2bf(acc1[i][1] + b1[cx + 1]) << 16);
        unsigned int hi = (unsigned int)f2bf(acc1[i][2] + b1[cx + 2])
                        | ((unsigned int)f2bf(acc1[i][3] + b1[cx + 3]) << 16);
        *(unsigned int*)&U1[base]     = lo;
        *(unsigned int*)&U1[base + 2] = hi;
    }

    // pass 2: W2 (re-reads As from LDS — cheap)
    f4 acc2[4];
#pragma unroll
    for (int i = 0; i < 4; ++i) acc2[i] = (f4)(0.f);
#pragma unroll 2
    for (int k = 0; k < 64; k += 4) {
        f4 a[4], w[4];
#pragma unroll
        for (int i = 0; i < 4; ++i) a[i] = *(const f4*)&As[ry + i][k];
#pragma unroll
        for (int kk = 0; kk < 4; ++kk) w[kk] = *(const f4*)&Wt2[k + kk][cx];
#pragma unroll
        for (int i = 0; i < 4; ++i)
#pragma unroll
            for (int kk = 0; kk < 4; ++kk) acc2[i] += a[i][kk] * w[kk];
    }
#pragma unroll
    for (int k2 = 64; k2 < 66; ++k2) {
        f4 w = *(const f4*)&Wt2[k2][cx];
#pragma unroll
        for (int i = 0; i < 4; ++i) acc2[i] += As[ry + i][k2] * w;
    }
#pragma unroll
    for (int i = 0; i < 4; ++i) {
        int grow = row0 + ry + i;
        if (grow >= N) break;
        size_t base = (size_t)grow * 64 + cx;
        unsigned int lo = (unsigned int)f2bf(acc2[i][0] + b2[cx + 0])
                        | ((unsigned int)f2bf(acc2[i][1] + b2[cx + 1]) << 16);
        unsigned int hi = (unsigned int)f2bf(acc2[i][2] + b2[cx + 2])
                        | ((unsigned int)f2bf(acc2[i][3] + b2[cx + 3]) << 16);
        *(unsigned int*)&U2[base]     = lo;
        *(unsigned int*)&U2[base + 2] = hi;
    }
}

// reg(4) + obj(1) heads fused, f32 output (tiny)
__global__ __launch_bounds__(256)
void gemm_regobj(const float* __restrict__ s, const float* __restrict__ pos,
                 const float* __restrict__ Wr, const float* __restrict__ br,
                 const float* __restrict__ Wo, const float* __restrict__ bo,
                 const float* __restrict__ ab,
                 float* __restrict__ uR, float* __restrict__ uO, int N) {
    __shared__ __attribute__((aligned(16))) float As[64][68];
    __shared__ float Wt[66][5];
    int row0 = blockIdx.x * 64;
    int tid  = threadIdx.x;
    stage_A(As, s, pos, ab, row0, N, tid);
    for (int idx = tid; idx < 66 * 5; idx += 256) {
        int c = idx / 66, k = idx - c * 66;
        Wt[k][c] = (c < 4) ? Wr[(size_t)c * 66 + k] : Wo[k];
    }
    __syncthreads();
    int r  = tid & 63;
    int cs = tid >> 6;     // 0..3
    int grow = row0 + r;
    if (grow >= N) return;
    float acc = 0.f, acco = 0.f;
    for (int k = 0; k < 66; ++k) {
        float a = As[r][k];
        acc += a * Wt[k][cs];
        if (cs == 0) acco += a * Wt[k][4];
    }
    uR[(size_t)grow * 4 + cs] = acc + br[cs];
    if (cs == 0) uO[grow] = acco + bo[0];
}

// ---------------- segment max, 64ch bf16, 2 nodes per wave ----------------
// lane 0-31 = channel pair (2l,2l+1); half-wave selects node parity.
// Per edge: 32 lanes x 4B = exactly one 128B row.

template <bool STATS>
__global__ __launch_bounds__(256)
void segmax64b(const unsigned short* __restrict__ U, const float* __restrict__ pos,
               const float* __restrict__ W, const int* __restrict__ offs,
               const int* __restrict__ csr, float* __restrict__ out,
               float* __restrict__ partials, int N) {
    int t    = threadIdx.x;
    int lane = t & 31;
    int half = (t >> 5) & 1;
    int wv   = t >> 6;
    int c0   = lane * 2;
    int gw   = blockIdx.x * 4 + wv;
    int nw   = gridDim.x * 4;
    float wa0 = W[c0 * 66 + 64],      wa1 = W[c0 * 66 + 65];
    float wb0 = W[(c0 + 1) * 66 + 64], wb1 = W[(c0 + 1) * 66 + 65];
    f2 sum = {0.f, 0.f}, sq = {0.f, 0.f};
    int half_n = (N + 1) >> 1;
    for (int p = gw; p < half_n; p += nw) {
        int i = 2 * p + half;
        if (i < N) {
            int s0 = offs[i], s1 = offs[i + 1];
            f2 m = { -INFINITY, -INFINITY };
            int e = s0;
            for (; e + 4 <= s1; e += 4) {
                int j0 = csr[e], j1 = csr[e + 1], j2 = csr[e + 2], j3 = csr[e + 3];
                unsigned int v0 = *(const unsigned int*)&U[(size_t)j0 * 64 + c0];
                unsigned int v1 = *(const unsigned int*)&U[(size_t)j1 * 64 + c0];
                unsigned int v2 = *(const unsigned int*)&U[(size_t)j2 * 64 + c0];
                unsigned int v3 = *(const unsigned int*)&U[(size_t)j3 * 64 + c0];
                f2 f0 = bf2(v0), f1 = bf2(v1), g2 = bf2(v2), g3 = bf2(v3);
                m.x = fmaxf(m.x, fmaxf(fmaxf(f0.x, f1.x), fmaxf(g2.x, g3.x)));
                m.y = fmaxf(m.y, fmaxf(fmaxf(f0.y, f1.y), fmaxf(g2.y, g3.y)));
            }
            for (; e < s1; ++e) {
                f2 f0 = bf2(*(const unsigned int*)&U[(size_t)csr[e] * 64 + c0]);
                m.x = fmaxf(m.x, f0.x);
                m.y = fmaxf(m.y, f0.y);
            }
            float p0 = pos[i * 3], p1 = pos[i * 3 + 1];
            f2 val = {0.f, 0.f};
            if (s1 > s0) {
                val.x = m.x - (p0 * wa0 + p1 * wa1);
                val.y = m.y - (p0 * wb0 + p1 * wb1);
            }
            *(f2*)&out[(size_t)i * 64 + c0] = val;
            if (STATS) {
                sum.x += val.x; sum.y += val.y;
                sq.x  += val.x * val.x; sq.y += val.y * val.y;
            }
        }
    }
    if (STATS) {
        __shared__ f2 ls[4][64];
        __shared__ f2 lq[4][64];
        ls[wv][t & 63] = sum;
        lq[wv][t & 63] = sq;
        __syncthreads();
        if (t < 32) {
            f2 S = {0.f, 0.f}, Q = {0.f, 0.f};
#pragma unroll
            for (int w = 0; w < 4; ++w) {
                f2 a = ls[w][t], b = ls[w][t + 32];
                S.x += a.x + b.x; S.y += a.y + b.y;
                f2 c = lq[w][t], d = lq[w][t + 32];
                Q.x += c.x + d.x; Q.y += c.y + d.y;
            }
            partials[blockIdx.x * 128 + 2 * t]       = S.x;
            partials[blockIdx.x * 128 + 2 * t + 1]   = S.y;
            partials[blockIdx.x * 128 + 64 + 2 * t]  = Q.x;
            partials[blockIdx.x * 128 + 65 + 2 * t]  = Q.y;
        }
    }
}

// ---------------- segment max, cls head (101ch bf16, padded to 102) ----------------

__global__ __launch_bounds__(256)
void segmax_clsb(const unsigned short* __restrict__ U, const float* __restrict__ pos,
                 const float* __restrict__ W, const int* __restrict__ offs,
                 const int* __restrict__ csr, float* __restrict__ out, int N) {
    int lane = threadIdx.x & 63;
    if (lane >= 51) return;               // no barriers below: safe
    int c0 = lane * 2, c1 = c0 + 1;
    int wv = threadIdx.x >> 6;
    int gg = blockIdx.x * 4 + wv;
    int ng = gridDim.x * 4;
    float wa0 = W[c0 * 66 + 64];
    float wa1 = W[c0 * 66 + 65];
    float wb0 = (c1 < NCLS) ? W[c1 * 66 + 64] : 0.f;
    float wb1 = (c1 < NCLS) ? W[c1 * 66 + 65] : 0.f;
    for (int i = gg; i < N; i += ng) {
        int s0 = offs[i], s1 = offs[i + 1];
        f2 m = { -INFINITY, -INFINITY };
        int e = s0;
        for (; e + 4 <= s1; e += 4) {
            int j0 = csr[e], j1 = csr[e + 1], j2 = csr[e + 2], j3 = csr[e + 3];
            f2 f0 = bf2(*(const unsigned int*)&U[(size_t)j0 * LDCLS + c0]);
            f2 f1 = bf2(*(const unsigned int*)&U[(size_t)j1 * LDCLS + c0]);
            f2 g2 = bf2(*(const unsigned int*)&U[(size_t)j2 * LDCLS + c0]);
            f2 g3 = bf2(*(const unsigned int*)&U[(size_t)j3 * LDCLS + c0]);
            m.x = fmaxf(m.x, fmaxf(fmaxf(f0.x, f1.x), fmaxf(g2.x, g3.x)));
            m.y = fmaxf(m.y, fmaxf(fmaxf(f0.y, f1.y), fmaxf(g2.y, g3.y)));
        }
        for (; e < s1; ++e) {
            f2 v = bf2(*(const unsigned int*)&U[(size_t)csr[e] * LDCLS + c0]);
            m.x = fmaxf(m.x, v.x);
            m.y = fmaxf(m.y, v.y);
        }
        float p0 = pos[i * 3], p1 = pos[i * 3 + 1];
        float va = 0.f, vb = 0.f;
        if (s1 > s0) {
            va = m.x - (p0 * wa0 + p1 * wa1);
            vb = m.y - (p0 * wb0 + p1 * wb1);
        }
        out[(size_t)i * NCLS + c0] = va;
        if (c1 < NCLS) out[(size_t)i * NCLS + c1] = vb;
    }
}

// ---------------- segment max, small OD (4 / 1), f32 ----------------

__global__ void segmax_small(const float* __restrict__ U, const float* __restrict__ pos,
                             const float* __restrict__ W, const int* __restrict__ offs,
                             const int* __restrict__ csr, float* __restrict__ out,
                             int N, int OD) {
    int t = blockIdx.x * blockDim.x + threadIdx.x;
    if (t >= N * OD) return;
    int i = t / OD;
    int c = t - i * OD;
    int s0 = offs[i], s1 = offs[i + 1];
    float m = -INFINITY;
    int e = s0;
    for (; e + 4 <= s1; e += 4) {
        int j0 = csr[e], j1 = csr[e + 1], j2 = csr[e + 2], j3 = csr[e + 3];
        float v0 = U[(size_t)j0 * OD + c];
        float v1 = U[(size_t)j1 * OD + c];
        float v2 = U[(size_t)j2 * OD + c];
        float v3 = U[(size_t)j3 * OD + c];
        m = fmaxf(m, fmaxf(fmaxf(v0, v1), fmaxf(v2, v3)));
    }
    for (; e < s1; ++e) m = fmaxf(m, U[(size_t)csr[e] * OD + c]);
    float val = 0.f;
    if (s1 > s0) val = m - (pos[i * 3] * W[c * 66 + 64] + pos[i * 3 + 1] * W[c * 66 + 65]);
    out[t] = val;
}

// ---------------- BN finalize: parallel tree reduce ----------------

__global__ __launch_bounds__(1024)
void bn_finalize(const float* __restrict__ partials, int N,
                 const float* __restrict__ g, const float* __restrict__ be,
                 float* __restrict__ ab) {
    __shared__ double ls[16][64];
    __shared__ double lq[16][64];
    int t = threadIdx.x;
    int c  = t & 63;
    int gr = t >> 6;          // 0..15
    double s = 0.0, q = 0.0;
#pragma unroll 8
    for (int b = 0; b < SEG_BLOCKS / 16; ++b) {
        int blk = gr * (SEG_BLOCKS / 16) + b;
        s += (double)partials[blk * 128 + c];
        q += (double)partials[blk * 128 + 64 + c];
    }
    ls[gr][c] = s; lq[gr][c] = q;
    __syncthreads();
    if (gr == 0) {
        double ss = 0.0, qq = 0.0;
#pragma unroll
        for (int i = 0; i < 16; ++i) { ss += ls[i][c]; qq += lq[i][c]; }
        double invN = 1.0 / (double)N;
        float m = (float)(ss * invN);
        float v = (float)(qq * invN) - m * m;
        float a = g[c] * rsqrtf(v + 1e-5f);
        ab[c]      = a;
        ab[64 + c] = be[c] - m * a;
    }
}

// ---------------- launch ----------------

extern "C" void kernel_launch(void* const* d_in, const int* in_sizes, int n_in,
                              void* d_out, int out_size, void* d_ws, size_t ws_size,
                              hipStream_t stream) {
    const float* x       = (const float*)d_in[0];
    const float* pos     = (const float*)d_in[1];
    const int*   ei      = (const int*)d_in[2];
    const float* W_stem  = (const float*)d_in[3];
    const float* b_stem  = (const float*)d_in[4];
    const float* W_conv1 = (const float*)d_in[5];
    const float* b_conv1 = (const float*)d_in[6];
    const float* W_conv2 = (const float*)d_in[7];
    const float* b_conv2 = (const float*)d_in[8];
    const float* W_regr  = (const float*)d_in[9];
    const float* b_regr  = (const float*)d_in[10];
    const float* W_cls   = (const float*)d_in[11];
    const float* b_cls   = (const float*)d_in[12];
    const float* W_obj   = (const float*)d_in[13];
    const float* b_obj   = (const float*)d_in[14];
    const float* g_stem  = (const float*)d_in[15];
    const float* be_stem = (const float*)d_in[16];
    const float* g_conv1 = (const float*)d_in[17];
    const float* be_conv1= (const float*)d_in[18];
    const float* g_conv2 = (const float*)d_in[19];
    const float* be_conv2= (const float*)d_in[20];

    const int N = in_sizes[0] / 64;
    const int E = in_sizes[2] / 2;
    const int* src = ei;
    const int* dst = ei + E;

    // ---- workspace layout (256B-aligned regions) ----
    char* ws = (char*)d_ws;
    size_t off = 0;
    auto carve = [&](size_t bytes) -> char* {
        char* p = ws + off;
        off += (bytes + 255) & ~(size_t)255;
        return p;
    };
    int*   counts   = (int*)carve((size_t)(N + 1) * 4);
    int*   offs     = (int*)carve((size_t)(N + 1) * 4);
    int*   wp       = (int*)carve((size_t)N * 4);
    int*   csr      = (int*)carve((size_t)E * 4);
    int*   blockSums= (int*)carve((size_t)SCAN_BLOCKS * 4);
    float* S1       = (float*)carve((size_t)N * 64 * 4);     // s_stem -> s1
    float* S2       = (float*)carve((size_t)N * 64 * 4);     // s2
    unsigned short* T1 = (unsigned short*)carve((size_t)N * 64 * 2);  // U_stem ; (T1+T2) reused as uCls
    unsigned short* T2 = (unsigned short*)carve((size_t)N * 64 * 2);  // U1
    unsigned short* T3 = (unsigned short*)carve((size_t)N * 64 * 2);  // U2
    float* uSmall   = (float*)carve((size_t)N * 5 * 4);      // uRegr (N*4) + uObj (N*1)
    float* partials = (float*)carve((size_t)SEG_BLOCKS * 128 * 4);
    float* abS      = (float*)carve(128 * 4);
    float* ab1      = (float*)carve(128 * 4);
    float* ab2      = (float*)carve(128 * 4);
    unsigned short* uCls = T1;          // N*102 bf16 = 20.4MB <= T1+T2 (25.6MB, contiguous)
    float* uRegr    = uSmall;
    float* uObj     = uSmall + (size_t)N * 4;

    float* out_cls = (float*)d_out;                       // N x 101
    float* out_reg = out_cls + (size_t)N * NCLS;          // N x 4
    float* out_obj = out_reg + (size_t)N * 4;             // N x 1

    const int eg = (E + 255) / 256;
    const dim3 blk(256);

    // ---- CSR build ----
    hipMemsetAsync(counts, 0, (size_t)(N + 1) * 4, stream);
    count_kernel<<<eg, blk, 0, stream>>>(dst, counts, E);
    partial_sum_kernel<<<SCAN_BLOCKS, blk, 0, stream>>>(counts, blockSums, N);
    scan_sums_kernel<<<1, SCAN_BLOCKS, 0, stream>>>(blockSums, offs, N);
    scan_apply_kernel<<<SCAN_BLOCKS, blk, 0, stream>>>(counts, blockSums, offs, wp, N);
    fill_kernel<<<eg, blk, 0, stream>>>(src, dst, wp, csr, E);

    const int ng64 = (N + 63) / 64;

    // ---- stem: U_stem = [x|pos2] @ Ws^T + b  (bf16) ----
    gemm_bf16<<<dim3(ng64, 1), blk, 0, stream>>>(x, pos, W_stem, b_stem, nullptr, T1, N, 64, 64);
    segmax64b<true><<<SEG_BLOCKS, blk, 0, stream>>>(T1, pos, W_stem, offs, csr, S1, partials, N);
    bn_finalize<<<1, 1024, 0, stream>>>(partials, N, g_stem, be_stem, abS);

    // ---- conv1 + conv2 (BN+ReLU of s_stem fused into A-stage) ----
    gemm_dual_bf16<<<dim3(ng64, 1), blk, 0, stream>>>(S1, pos, W_conv1, b_conv1,
                                                      W_conv2, b_conv2, abS, T2, T3, N);
    segmax64b<true><<<SEG_BLOCKS, blk, 0, stream>>>(T2, pos, W_conv1, offs, csr, S1, partials, N);
    bn_finalize<<<1, 1024, 0, stream>>>(partials, N, g_conv1, be_conv1, ab1);
    segmax64b<true><<<SEG_BLOCKS, blk, 0, stream>>>(T3, pos, W_conv2, offs, csr, S2, partials, N);
    bn_finalize<<<1, 1024, 0, stream>>>(partials, N, g_conv2, be_conv2, ab2);

    // ---- heads (BN+ReLU fused into A-stage) ----
    gemm_regobj<<<dim3(ng64, 1), blk, 0, stream>>>(S1, pos, W_regr, b_regr,
                                                   W_obj, b_obj, ab1, uRegr, uObj, N);
    gemm_bf16<<<dim3(ng64, 2), blk, 0, stream>>>(S2, pos, W_cls, b_cls, ab2,
                                                 uCls, N, NCLS, LDCLS);

    segmax_clsb<<<SEG_BLOCKS, blk, 0, stream>>>(uCls, pos, W_cls, offs, csr, out_cls, N);
    segmax_small<<<(N * 4 + 255) / 256, blk, 0, stream>>>(uRegr, pos, W_regr, offs, csr, out_reg, N, 4);
    segmax_small<<<(N + 255) / 256, blk, 0, stream>>>(uObj, pos, W_obj, offs, csr, out_obj, N, 1);
}

// Round 7
// 422.764 us; speedup vs baseline: 12.4114x; 1.2911x over previous
//
#include <hip/hip_runtime.h>
#include <math.h>

#define C64 64
#define CIN 66
#define NCLS 101
#define LDCLS 102          // padded bf16 row stride for U_cls
#define SEG_BLOCKS 2048    // fixed grid for segmax kernels (deterministic stats slots)
#define NPB 1024           // nodes per bucket (CSR build)
#define KMAX 128           // max buckets (N <= 131072; here N=100K -> K=98)
#define BINB 512           // binning blocks

typedef float f4 __attribute__((ext_vector_type(4)));
typedef float f2 __attribute__((ext_vector_type(2)));

// bf16 helpers (RNE pack, shift expand)
__device__ __forceinline__ unsigned short f2bf(float f) {
    unsigned int u = __float_as_uint(f);
    u += 0x7fffu + ((u >> 16) & 1u);
    return (unsigned short)(u >> 16);
}
__device__ __forceinline__ f2 bf2(unsigned int u) {
    f2 r;
    r.x = __uint_as_float(u << 16);
    r.y = __uint_as_float(u & 0xffff0000u);
    return r;
}

// ---------------- CSR build: two-level bucket sort ----------------
// Segment-max consumes csr as a SET per node, so within-segment order is free.
// Level 1 groups edges by 1024-node bucket with contiguous per-(block,bucket)
// runs (no write amplification, LDS-only atomics). Level 2 builds exact
// per-node CSR within each bucket (writes confined to one L2-resident slice).

__global__ __launch_bounds__(256)
void hist_kernel(const int* __restrict__ dst, int* __restrict__ ghist, int E, int K) {
    __shared__ int lhist[KMAX];
    int b = blockIdx.x;
    int C = (E + gridDim.x - 1) / gridDim.x;
    int lo = b * C, hi = lo + C; if (hi > E) hi = E;
    for (int k = threadIdx.x; k < K; k += 256) lhist[k] = 0;
    __syncthreads();
    for (int e = lo + threadIdx.x; e < hi; e += 256)
        atomicAdd(&lhist[dst[e] >> 10], 1);
    __syncthreads();
    for (int k = threadIdx.x; k < K; k += 256) ghist[k * BINB + b] = lhist[k];
}

__global__ __launch_bounds__(BINB)
void scan_hist_kernel(int* __restrict__ ghist, int* __restrict__ tot, int K) {
    __shared__ int buf[2][BINB];
    int k = blockIdx.x;
    int t = threadIdx.x;
    int v = ghist[k * BINB + t];
    buf[0][t] = v;
    __syncthreads();
    int cur = 0;
    for (int off = 1; off < BINB; off <<= 1) {
        int nv = buf[cur][t];
        if (t >= off) nv += buf[cur][t - off];
        buf[cur ^ 1][t] = nv;
        cur ^= 1;
        __syncthreads();
    }
    ghist[k * BINB + t] = buf[cur][t] - v;     // exclusive base within bucket
    if (t == BINB - 1) tot[k] = buf[cur][t];
}

__global__ __launch_bounds__(KMAX)
void scan_tot_kernel(const int* __restrict__ tot, int* __restrict__ bstart,
                     int* __restrict__ offs, int K, int N, int E) {
    __shared__ int buf[2][KMAX];
    int t = threadIdx.x;
    int v = (t < K) ? tot[t] : 0;
    buf[0][t] = v;
    __syncthreads();
    int cur = 0;
    for (int off = 1; off < KMAX; off <<= 1) {
        int nv = buf[cur][t];
        if (t >= off) nv += buf[cur][t - off];
        buf[cur ^ 1][t] = nv;
        cur ^= 1;
        __syncthreads();
    }
    if (t < K) bstart[t] = buf[cur][t] - v;
    if (t == 0) { bstart[K] = E; offs[N] = E; }
}

__global__ __launch_bounds__(256)
void scatter_kernel(const int* __restrict__ src, const int* __restrict__ dst,
                    const int* __restrict__ ghist, const int* __restrict__ bstart,
                    unsigned int* __restrict__ staged, int E, int K) {
    __shared__ int lbase[KMAX];
    int b = blockIdx.x;
    int C = (E + gridDim.x - 1) / gridDim.x;
    int lo = b * C, hi = lo + C; if (hi > E) hi = E;
    for (int k = threadIdx.x; k < K; k += 256)
        lbase[k] = bstart[k] + ghist[k * BINB + b];
    __syncthreads();
    for (int e = lo + threadIdx.x; e < hi; e += 256) {
        int d = dst[e];
        int k = d >> 10;
        int p = atomicAdd(&lbase[k], 1);
        staged[p] = (unsigned int)src[e] | ((unsigned int)(d & (NPB - 1)) << 17);
    }
}

__global__ __launch_bounds__(1024)
void build_kernel(const unsigned int* __restrict__ staged, const int* __restrict__ bstart,
                  int* __restrict__ offs, int* __restrict__ csr, int N) {
    __shared__ int cnt[1024];
    __shared__ int buf[1024];
    int k = blockIdx.x;
    int t = threadIdx.x;
    int e0 = bstart[k], e1 = bstart[k + 1];
    cnt[t] = 0;
    __syncthreads();
    for (int p = e0 + t; p < e1; p += 1024)
        atomicAdd(&cnt[staged[p] >> 17], 1);
    __syncthreads();
    int myc = cnt[t];
    // inclusive scan, ping-pong (10 steps: ends in cnt)
    int* a = cnt; int* bb = buf;
    for (int off = 1; off < 1024; off <<= 1) {
        int v = a[t];
        if (t >= off) v += a[t - off];
        bb[t] = v;
        __syncthreads();
        int* tmp = a; a = bb; bb = tmp;
    }
    int excl = a[t] - myc;
    int node = k * NPB + t;
    if (node < N) offs[node] = e0 + excl;
    bb[t] = excl;            // bb is the free array: per-node write pointer
    __syncthreads();
    for (int p = e0 + t; p < e1; p += 1024) {
        unsigned int v = staged[p];
        int n = v >> 17;
        int q = atomicAdd(&bb[n], 1);
        csr[e0 + q] = (int)(v & 0x1FFFFu);
    }
}

// ---------------- GEMM helpers ----------------
// stage A tile: optional fused BN+ReLU on the 64 feature channels (ab != nullptr)

__device__ __forceinline__ void stage_A(float (*As)[68], const float* __restrict__ feat,
                                        const float* __restrict__ pos, const float* __restrict__ ab,
                                        int row0, int N, int tid) {
    for (int idx = tid; idx < 64 * 66; idx += 256) {
        int r = idx / 66, k = idx - r * 66;
        int grow = row0 + r;
        float v = 0.f;
        if (grow < N) {
            if (k < 64) {
                v = feat[(size_t)grow * 64 + k];
                if (ab) v = fmaxf(0.f, v * ab[k] + ab[64 + k]);
            } else {
                v = pos[(size_t)grow * 3 + (k - 64)];
            }
        }
        As[r][k] = v;
    }
}

// general GEMM -> bf16 output (used for stem U and cls U)
__global__ __launch_bounds__(256)
void gemm_bf16(const float* __restrict__ feat, const float* __restrict__ pos,
               const float* __restrict__ W, const float* __restrict__ bias,
               const float* __restrict__ ab, unsigned short* __restrict__ U,
               int N, int OD, int ldU) {
    __shared__ __attribute__((aligned(16))) float As[64][68];
    __shared__ __attribute__((aligned(16))) float Wt[66][68];
    int row0 = blockIdx.x * 64;
    int c0b  = blockIdx.y * 64;
    int tid  = threadIdx.x;

    stage_A(As, feat, pos, ab, row0, N, tid);
    for (int idx = tid; idx < 64 * 66; idx += 256) {
        int c = idx / 66, k = idx - c * 66;
        float v = 0.f;
        if (c0b + c < OD) v = W[(size_t)(c0b + c) * 66 + k];
        Wt[k][c] = v;
    }
    __syncthreads();

    const int cx = (tid & 15) * 4;
    const int ry = (tid >> 4) * 4;

    f4 acc[4];
#pragma unroll
    for (int i = 0; i < 4; ++i) acc[i] = (f4)(0.f);

#pragma unroll 2
    for (int k = 0; k < 64; k += 4) {
        f4 a[4], w[4];
#pragma unroll
        for (int i = 0; i < 4; ++i) a[i] = *(const f4*)&As[ry + i][k];
#pragma unroll
        for (int kk = 0; kk < 4; ++kk) w[kk] = *(const f4*)&Wt[k + kk][cx];
#pragma unroll
        for (int i = 0; i < 4; ++i)
#pragma unroll
            for (int kk = 0; kk < 4; ++kk) acc[i] += a[i][kk] * w[kk];
    }
#pragma unroll
    for (int k2 = 64; k2 < 66; ++k2) {
        f4 w = *(const f4*)&Wt[k2][cx];
#pragma unroll
        for (int i = 0; i < 4; ++i) acc[i] += As[ry + i][k2] * w;
    }

    int c = c0b + cx;
#pragma unroll
    for (int i = 0; i < 4; ++i) {
        int grow = row0 + ry + i;
        if (grow >= N) break;
        size_t base = (size_t)grow * ldU + c;
        if (c + 3 < OD) {
            unsigned int lo = (unsigned int)f2bf(acc[i][0] + bias[c + 0])
                            | ((unsigned int)f2bf(acc[i][1] + bias[c + 1]) << 16);
            unsigned int hi = (unsigned int)f2bf(acc[i][2] + bias[c + 2])
                            | ((unsigned int)f2bf(acc[i][3] + bias[c + 3]) << 16);
            *(unsigned int*)&U[base]     = lo;
            *(unsigned int*)&U[base + 2] = hi;
        } else {
#pragma unroll
            for (int j = 0; j < 4; ++j)
                if (c + j < OD) U[base + j] = f2bf(acc[i][j] + bias[c + j]);
        }
    }
}

// dual GEMM (conv1 + conv2 share the normalized input tile)
__global__ __launch_bounds__(256)
void gemm_dual_bf16(const float* __restrict__ s, const float* __restrict__ pos,
                    const float* __restrict__ W1, const float* __restrict__ b1,
                    const float* __restrict__ W2, const float* __restrict__ b2,
                    const float* __restrict__ ab,
                    unsigned short* __restrict__ U1, unsigned short* __restrict__ U2, int N) {
    __shared__ __attribute__((aligned(16))) float As[64][68];
    __shared__ __attribute__((aligned(16))) float Wt1[66][68];
    __shared__ __attribute__((aligned(16))) float Wt2[66][68];
    int row0 = blockIdx.x * 64;
    int tid  = threadIdx.x;

    stage_A(As, s, pos, ab, row0, N, tid);
    for (int idx = tid; idx < 64 * 66; idx += 256) {
        int c = idx / 66, k = idx - c * 66;
        Wt1[k][c] = W1[(size_t)c * 66 + k];
        Wt2[k][c] = W2[(size_t)c * 66 + k];
    }
    __syncthreads();

    const int cx = (tid & 15) * 4;
    const int ry = (tid >> 4) * 4;

    f4 acc1[4];
#pragma unroll
    for (int i = 0; i < 4; ++i) acc1[i] = (f4)(0.f);
#pragma unroll 2
    for (int k = 0; k < 64; k += 4) {
        f4 a[4], w[4];
#pragma unroll
        for (int i = 0; i < 4; ++i) a[i] = *(const f4*)&As[ry + i][k];
#pragma unroll
        for (int kk = 0; kk < 4; ++kk) w[kk] = *(const f4*)&Wt1[k + kk][cx];
#pragma unroll
        for (int i = 0; i < 4; ++i)
#pragma unroll
            for (int kk = 0; kk < 4; ++kk) acc1[i] += a[i][kk] * w[kk];
    }
#pragma unroll
    for (int k2 = 64; k2 < 66; ++k2) {
        f4 w = *(const f4*)&Wt1[k2][cx];
#pragma unroll
        for (int i = 0; i < 4; ++i) acc1[i] += As[ry + i][k2] * w;
    }
#pragma unroll
    for (int i = 0; i < 4; ++i) {
        int grow = row0 + ry + i;
        if (grow >= N) break;
        size_t base = (size_t)grow * 64 + cx;
        unsigned int lo = (unsigned int)f2bf(acc1[i][0] + b1[cx + 0])
                        | ((unsigned int)f2bf(acc1[i][1] + b1[cx + 1]) << 16);
        unsigned int hi = (unsigned int)f2bf(acc1[i][2] + b1[cx + 2])
                        | ((unsigned int)f2bf(acc1[i][3] + b1[cx + 3]) << 16);
        *(unsigned int*)&U1[base]     = lo;
        *(unsigned int*)&U1[base + 2] = hi;
    }

    f4 acc2[4];
#pragma unroll
    for (int i = 0; i < 4; ++i) acc2[i] = (f4)(0.f);
#pragma unroll 2
    for (int k = 0; k < 64; k += 4) {
        f4 a[4], w[4];
#pragma unroll
        for (int i = 0; i < 4; ++i) a[i] = *(const f4*)&As[ry + i][k];
#pragma unroll
        for (int kk = 0; kk < 4; ++kk) w[kk] = *(const f4*)&Wt2[k + kk][cx];
#pragma unroll
        for (int i = 0; i < 4; ++i)
#pragma unroll
            for (int kk = 0; kk < 4; ++kk) acc2[i] += a[i][kk] * w[kk];
    }
#pragma unroll
    for (int k2 = 64; k2 < 66; ++k2) {
        f4 w = *(const f4*)&Wt2[k2][cx];
#pragma unroll
        for (int i = 0; i < 4; ++i) acc2[i] += As[ry + i][k2] * w;
    }
#pragma unroll
    for (int i = 0; i < 4; ++i) {
        int grow = row0 + ry + i;
        if (grow >= N) break;
        size_t base = (size_t)grow * 64 + cx;
        unsigned int lo = (unsigned int)f2bf(acc2[i][0] + b2[cx + 0])
                        | ((unsigned int)f2bf(acc2[i][1] + b2[cx + 1]) << 16);
        unsigned int hi = (unsigned int)f2bf(acc2[i][2] + b2[cx + 2])
                        | ((unsigned int)f2bf(acc2[i][3] + b2[cx + 3]) << 16);
        *(unsigned int*)&U2[base]     = lo;
        *(unsigned int*)&U2[base + 2] = hi;
    }
}

// reg(4) + obj(1) heads fused, f32 output (tiny)
__global__ __launch_bounds__(256)
void gemm_regobj(const float* __restrict__ s, const float* __restrict__ pos,
                 const float* __restrict__ Wr, const float* __restrict__ br,
                 const float* __restrict__ Wo, const float* __restrict__ bo,
                 const float* __restrict__ ab,
                 float* __restrict__ uR, float* __restrict__ uO, int N) {
    __shared__ __attribute__((aligned(16))) float As[64][68];
    __shared__ float Wt[66][5];
    int row0 = blockIdx.x * 64;
    int tid  = threadIdx.x;
    stage_A(As, s, pos, ab, row0, N, tid);
    for (int idx = tid; idx < 66 * 5; idx += 256) {
        int c = idx / 66, k = idx - c * 66;
        Wt[k][c] = (c < 4) ? Wr[(size_t)c * 66 + k] : Wo[k];
    }
    __syncthreads();
    int r  = tid & 63;
    int cs = tid >> 6;     // 0..3
    int grow = row0 + r;
    if (grow >= N) return;
    float acc = 0.f, acco = 0.f;
    for (int k = 0; k < 66; ++k) {
        float a = As[r][k];
        acc += a * Wt[k][cs];
        if (cs == 0) acco += a * Wt[k][4];
    }
    uR[(size_t)grow * 4 + cs] = acc + br[cs];
    if (cs == 0) uO[grow] = acco + bo[0];
}

// ---------------- segment max, 64ch bf16, 2 nodes per wave ----------------

template <bool STATS>
__global__ __launch_bounds__(256)
void segmax64b(const unsigned short* __restrict__ U, const float* __restrict__ pos,
               const float* __restrict__ W, const int* __restrict__ offs,
               const int* __restrict__ csr, float* __restrict__ out,
               float* __restrict__ partials, int N) {
    int t    = threadIdx.x;
    int lane = t & 31;
    int half = (t >> 5) & 1;
    int wv   = t >> 6;
    int c0   = lane * 2;
    int gw   = blockIdx.x * 4 + wv;
    int nw   = gridDim.x * 4;
    float wa0 = W[c0 * 66 + 64],      wa1 = W[c0 * 66 + 65];
    float wb0 = W[(c0 + 1) * 66 + 64], wb1 = W[(c0 + 1) * 66 + 65];
    f2 sum = {0.f, 0.f}, sq = {0.f, 0.f};
    int half_n = (N + 1) >> 1;
    for (int p = gw; p < half_n; p += nw) {
        int i = 2 * p + half;
        if (i < N) {
            int s0 = offs[i], s1 = offs[i + 1];
            f2 m = { -INFINITY, -INFINITY };
            int e = s0;
            for (; e + 4 <= s1; e += 4) {
                int j0 = csr[e], j1 = csr[e + 1], j2 = csr[e + 2], j3 = csr[e + 3];
                unsigned int v0 = *(const unsigned int*)&U[(size_t)j0 * 64 + c0];
                unsigned int v1 = *(const unsigned int*)&U[(size_t)j1 * 64 + c0];
                unsigned int v2 = *(const unsigned int*)&U[(size_t)j2 * 64 + c0];
                unsigned int v3 = *(const unsigned int*)&U[(size_t)j3 * 64 + c0];
                f2 f0 = bf2(v0), f1 = bf2(v1), g2 = bf2(v2), g3 = bf2(v3);
                m.x = fmaxf(m.x, fmaxf(fmaxf(f0.x, f1.x), fmaxf(g2.x, g3.x)));
                m.y = fmaxf(m.y, fmaxf(fmaxf(f0.y, f1.y), fmaxf(g2.y, g3.y)));
            }
            for (; e < s1; ++e) {
                f2 f0 = bf2(*(const unsigned int*)&U[(size_t)csr[e] * 64 + c0]);
                m.x = fmaxf(m.x, f0.x);
                m.y = fmaxf(m.y, f0.y);
            }
            float p0 = pos[i * 3], p1 = pos[i * 3 + 1];
            f2 val = {0.f, 0.f};
            if (s1 > s0) {
                val.x = m.x - (p0 * wa0 + p1 * wa1);
                val.y = m.y - (p0 * wb0 + p1 * wb1);
            }
            *(f2*)&out[(size_t)i * 64 + c0] = val;
            if (STATS) {
                sum.x += val.x; sum.y += val.y;
                sq.x  += val.x * val.x; sq.y += val.y * val.y;
            }
        }
    }
    if (STATS) {
        __shared__ f2 ls[4][64];
        __shared__ f2 lq[4][64];
        ls[wv][t & 63] = sum;
        lq[wv][t & 63] = sq;
        __syncthreads();
        if (t < 32) {
            f2 S = {0.f, 0.f}, Q = {0.f, 0.f};
#pragma unroll
            for (int w = 0; w < 4; ++w) {
                f2 a = ls[w][t], b = ls[w][t + 32];
                S.x += a.x + b.x; S.y += a.y + b.y;
                f2 c = lq[w][t], d = lq[w][t + 32];
                Q.x += c.x + d.x; Q.y += c.y + d.y;
            }
            partials[blockIdx.x * 128 + 2 * t]       = S.x;
            partials[blockIdx.x * 128 + 2 * t + 1]   = S.y;
            partials[blockIdx.x * 128 + 64 + 2 * t]  = Q.x;
            partials[blockIdx.x * 128 + 65 + 2 * t]  = Q.y;
        }
    }
}

// ---------------- segment max, cls head (101ch bf16, padded to 102) ----------------

__global__ __launch_bounds__(256)
void segmax_clsb(const unsigned short* __restrict__ U, const float* __restrict__ pos,
                 const float* __restrict__ W, const int* __restrict__ offs,
                 const int* __restrict__ csr, float* __restrict__ out, int N) {
    int lane = threadIdx.x & 63;
    if (lane >= 51) return;               // no barriers below: safe
    int c0 = lane * 2, c1 = c0 + 1;
    int wv = threadIdx.x >> 6;
    int gg = blockIdx.x * 4 + wv;
    int ng = gridDim.x * 4;
    float wa0 = W[c0 * 66 + 64];
    float wa1 = W[c0 * 66 + 65];
    float wb0 = (c1 < NCLS) ? W[c1 * 66 + 64] : 0.f;
    float wb1 = (c1 < NCLS) ? W[c1 * 66 + 65] : 0.f;
    for (int i = gg; i < N; i += ng) {
        int s0 = offs[i], s1 = offs[i + 1];
        f2 m = { -INFINITY, -INFINITY };
        int e = s0;
        for (; e + 4 <= s1; e += 4) {
            int j0 = csr[e], j1 = csr[e + 1], j2 = csr[e + 2], j3 = csr[e + 3];
            f2 f0 = bf2(*(const unsigned int*)&U[(size_t)j0 * LDCLS + c0]);
            f2 f1 = bf2(*(const unsigned int*)&U[(size_t)j1 * LDCLS + c0]);
            f2 g2 = bf2(*(const unsigned int*)&U[(size_t)j2 * LDCLS + c0]);
            f2 g3 = bf2(*(const unsigned int*)&U[(size_t)j3 * LDCLS + c0]);
            m.x = fmaxf(m.x, fmaxf(fmaxf(f0.x, f1.x), fmaxf(g2.x, g3.x)));
            m.y = fmaxf(m.y, fmaxf(fmaxf(f0.y, f1.y), fmaxf(g2.y, g3.y)));
        }
        for (; e < s1; ++e) {
            f2 v = bf2(*(const unsigned int*)&U[(size_t)csr[e] * LDCLS + c0]);
            m.x = fmaxf(m.x, v.x);
            m.y = fmaxf(m.y, v.y);
        }
        float p0 = pos[i * 3], p1 = pos[i * 3 + 1];
        float va = 0.f, vb = 0.f;
        if (s1 > s0) {
            va = m.x - (p0 * wa0 + p1 * wa1);
            vb = m.y - (p0 * wb0 + p1 * wb1);
        }
        out[(size_t)i * NCLS + c0] = va;
        if (c1 < NCLS) out[(size_t)i * NCLS + c1] = vb;
    }
}

// ---------------- segment max, small OD (4 / 1), f32 ----------------

__global__ void segmax_small(const float* __restrict__ U, const float* __restrict__ pos,
                             const float* __restrict__ W, const int* __restrict__ offs,
                             const int* __restrict__ csr, float* __restrict__ out,
                             int N, int OD) {
    int t = blockIdx.x * blockDim.x + threadIdx.x;
    if (t >= N * OD) return;
    int i = t / OD;
    int c = t - i * OD;
    int s0 = offs[i], s1 = offs[i + 1];
    float m = -INFINITY;
    int e = s0;
    for (; e + 4 <= s1; e += 4) {
        int j0 = csr[e], j1 = csr[e + 1], j2 = csr[e + 2], j3 = csr[e + 3];
        float v0 = U[(size_t)j0 * OD + c];
        float v1 = U[(size_t)j1 * OD + c];
        float v2 = U[(size_t)j2 * OD + c];
        float v3 = U[(size_t)j3 * OD + c];
        m = fmaxf(m, fmaxf(fmaxf(v0, v1), fmaxf(v2, v3)));
    }
    for (; e < s1; ++e) m = fmaxf(m, U[(size_t)csr[e] * OD + c]);
    float val = 0.f;
    if (s1 > s0) val = m - (pos[i * 3] * W[c * 66 + 64] + pos[i * 3 + 1] * W[c * 66 + 65]);
    out[t] = val;
}

// ---------------- BN finalize: parallel tree reduce ----------------

__global__ __launch_bounds__(1024)
void bn_finalize(const float* __restrict__ partials, int N,
                 const float* __restrict__ g, const float* __restrict__ be,
                 float* __restrict__ ab) {
    __shared__ double ls[16][64];
    __shared__ double lq[16][64];
    int t = threadIdx.x;
    int c  = t & 63;
    int gr = t >> 6;          // 0..15
    double s = 0.0, q = 0.0;
#pragma unroll 8
    for (int b = 0; b < SEG_BLOCKS / 16; ++b) {
        int blk = gr * (SEG_BLOCKS / 16) + b;
        s += (double)partials[blk * 128 + c];
        q += (double)partials[blk * 128 + 64 + c];
    }
    ls[gr][c] = s; lq[gr][c] = q;
    __syncthreads();
    if (gr == 0) {
        double ss = 0.0, qq = 0.0;
#pragma unroll
        for (int i = 0; i < 16; ++i) { ss += ls[i][c]; qq += lq[i][c]; }
        double invN = 1.0 / (double)N;
        float m = (float)(ss * invN);
        float v = (float)(qq * invN) - m * m;
        float a = g[c] * rsqrtf(v + 1e-5f);
        ab[c]      = a;
        ab[64 + c] = be[c] - m * a;
    }
}

// ---------------- launch ----------------

extern "C" void kernel_launch(void* const* d_in, const int* in_sizes, int n_in,
                              void* d_out, int out_size, void* d_ws, size_t ws_size,
                              hipStream_t stream) {
    const float* x       = (const float*)d_in[0];
    const float* pos     = (const float*)d_in[1];
    const int*   ei      = (const int*)d_in[2];
    const float* W_stem  = (const float*)d_in[3];
    const float* b_stem  = (const float*)d_in[4];
    const float* W_conv1 = (const float*)d_in[5];
    const float* b_conv1 = (const float*)d_in[6];
    const float* W_conv2 = (const float*)d_in[7];
    const float* b_conv2 = (const float*)d_in[8];
    const float* W_regr  = (const float*)d_in[9];
    const float* b_regr  = (const float*)d_in[10];
    const float* W_cls   = (const float*)d_in[11];
    const float* b_cls   = (const float*)d_in[12];
    const float* W_obj   = (const float*)d_in[13];
    const float* b_obj   = (const float*)d_in[14];
    const float* g_stem  = (const float*)d_in[15];
    const float* be_stem = (const float*)d_in[16];
    const float* g_conv1 = (const float*)d_in[17];
    const float* be_conv1= (const float*)d_in[18];
    const float* g_conv2 = (const float*)d_in[19];
    const float* be_conv2= (const float*)d_in[20];

    const int N = in_sizes[0] / 64;
    const int E = in_sizes[2] / 2;
    const int* src = ei;
    const int* dst = ei + E;
    const int K = (N + NPB - 1) / NPB;      // buckets (98 for N=100K; K<=KMAX)

    // ---- workspace layout (256B-aligned regions) ----
    char* ws = (char*)d_ws;
    size_t off = 0;
    auto carve = [&](size_t bytes) -> char* {
        char* p = ws + off;
        off += (bytes + 255) & ~(size_t)255;
        return p;
    };
    int*   offs     = (int*)carve((size_t)(N + 1) * 4);
    int*   csr      = (int*)carve((size_t)E * 4);
    unsigned int* staged = (unsigned int*)carve((size_t)E * 4);
    int*   ghist    = (int*)carve((size_t)KMAX * BINB * 4);
    int*   tot      = (int*)carve((size_t)KMAX * 4);
    int*   bstart   = (int*)carve((size_t)(KMAX + 1) * 4);
    float* S1       = (float*)carve((size_t)N * 64 * 4);     // s_stem -> s1
    float* S2       = (float*)carve((size_t)N * 64 * 4);     // s2
    unsigned short* T1 = (unsigned short*)carve((size_t)N * 64 * 2);  // U_stem ; (T1+T2) reused as uCls
    unsigned short* T2 = (unsigned short*)carve((size_t)N * 64 * 2);  // U1
    unsigned short* T3 = (unsigned short*)carve((size_t)N * 64 * 2);  // U2
    float* uSmall   = (float*)carve((size_t)N * 5 * 4);      // uRegr (N*4) + uObj (N*1)
    float* partials = (float*)carve((size_t)SEG_BLOCKS * 128 * 4);
    float* abS      = (float*)carve(128 * 4);
    float* ab1      = (float*)carve(128 * 4);
    float* ab2      = (float*)carve(128 * 4);
    unsigned short* uCls = T1;          // N*102 bf16 = 20.4MB <= T1+T2 (25.6MB, contiguous)
    float* uRegr    = uSmall;
    float* uObj     = uSmall + (size_t)N * 4;

    float* out_cls = (float*)d_out;                       // N x 101
    float* out_reg = out_cls + (size_t)N * NCLS;          // N x 4
    float* out_obj = out_reg + (size_t)N * 4;             // N x 1

    const dim3 blk(256);

    // ---- CSR build (two-level bucket sort; no global atomics, no write amp) ----
    hist_kernel<<<BINB, blk, 0, stream>>>(dst, ghist, E, K);
    scan_hist_kernel<<<K, BINB, 0, stream>>>(ghist, tot, K);
    scan_tot_kernel<<<1, KMAX, 0, stream>>>(tot, bstart, offs, K, N, E);
    scatter_kernel<<<BINB, blk, 0, stream>>>(src, dst, ghist, bstart, staged, E, K);
    build_kernel<<<K, 1024, 0, stream>>>(staged, bstart, offs, csr, N);

    const int ng64 = (N + 63) / 64;

    // ---- stem: U_stem = [x|pos2] @ Ws^T + b  (bf16) ----
    gemm_bf16<<<dim3(ng64, 1), blk, 0, stream>>>(x, pos, W_stem, b_stem, nullptr, T1, N, 64, 64);
    segmax64b<true><<<SEG_BLOCKS, blk, 0, stream>>>(T1, pos, W_stem, offs, csr, S1, partials, N);
    bn_finalize<<<1, 1024, 0, stream>>>(partials, N, g_stem, be_stem, abS);

    // ---- conv1 + conv2 (BN+ReLU of s_stem fused into A-stage) ----
    gemm_dual_bf16<<<dim3(ng64, 1), blk, 0, stream>>>(S1, pos, W_conv1, b_conv1,
                                                      W_conv2, b_conv2, abS, T2, T3, N);
    segmax64b<true><<<SEG_BLOCKS, blk, 0, stream>>>(T2, pos, W_conv1, offs, csr, S1, partials, N);
    bn_finalize<<<1, 1024, 0, stream>>>(partials, N, g_conv1, be_conv1, ab1);
    segmax64b<true><<<SEG_BLOCKS, blk, 0, stream>>>(T3, pos, W_conv2, offs, csr, S2, partials, N);
    bn_finalize<<<1, 1024, 0, stream>>>(partials, N, g_conv2, be_conv2, ab2);

    // ---- heads (BN+ReLU fused into A-stage) ----
    gemm_regobj<<<dim3(ng64, 1), blk, 0, stream>>>(S1, pos, W_regr, b_regr,
                                                   W_obj, b_obj, ab1, uRegr, uObj, N);
    gemm_bf16<<<dim3(ng64, 2), blk, 0, stream>>>(S2, pos, W_cls, b_cls, ab2,
                                                 uCls, N, NCLS, LDCLS);

    segmax_clsb<<<SEG_BLOCKS, blk, 0, stream>>>(uCls, pos, W_cls, offs, csr, out_cls, N);
    segmax_small<<<(N * 4 + 255) / 256, blk, 0, stream>>>(uRegr, pos, W_regr, offs, csr, out_reg, N, 4);
    segmax_small<<<(N + 255) / 256, blk, 0, stream>>>(uObj, pos, W_obj, offs, csr, out_obj, N, 1);
}